// Round 2
// baseline (912.013 us; speedup 1.0000x reference)
//
#include <hip/hip_runtime.h>

typedef unsigned short u16;
typedef unsigned int u32;
typedef __attribute__((ext_vector_type(8))) __bf16 bf16x8;
typedef __attribute__((ext_vector_type(4))) float f32x4;

// ---------- helpers ----------
__device__ __forceinline__ u16 f2bf(float f) {
  u32 u = __float_as_uint(f);
  u32 r = (u + 0x7FFFu + ((u >> 16) & 1u)) >> 16;  // RNE
  return (u16)r;
}

__device__ __forceinline__ void gload_lds16(const void* g, void* l) {
  __builtin_amdgcn_global_load_lds((const __attribute__((address_space(1))) u32*)g,
                                   (__attribute__((address_space(3))) u32*)l, 16, 0, 0);
}

__device__ __forceinline__ float fast_tanh(float x) {
  x = fminf(fmaxf(x, -15.f), 15.f);
  float e2 = __expf(2.f * x);
  return (e2 - 1.f) / (e2 + 1.f);
}

// ---------- fp32 -> bf16 convert (vectorized, float4 granular) ----------
__global__ __launch_bounds__(256) void cvt_kernel(const float* __restrict__ src,
                                                  u16* __restrict__ dst, int n4) {
  int i = blockIdx.x * blockDim.x + threadIdx.x;
  if (i >= n4) return;
  float4 v = reinterpret_cast<const float4*>(src)[i];
  ushort4 o;
  o.x = f2bf(v.x); o.y = f2bf(v.y); o.z = f2bf(v.z); o.w = f2bf(v.w);
  reinterpret_cast<ushort4*>(dst)[i] = o;
}

// ---------- merged small converts: query (4096 blocks) | Ua (1024) | Wa (1024) ----------
__global__ __launch_bounds__(256) void cvt3_kernel(const float* __restrict__ q_src, u16* __restrict__ q_dst,
                                                   const float* __restrict__ u_src, u16* __restrict__ u_dst,
                                                   const float* __restrict__ w_src, u16* __restrict__ w_dst) {
  int b = blockIdx.x;
  const float* src; u16* dst; int i;
  if (b < 4096)      { src = q_src; dst = q_dst; i = b * 256 + threadIdx.x; }
  else if (b < 5120) { src = u_src; dst = u_dst; i = (b - 4096) * 256 + threadIdx.x; }
  else               { src = w_src; dst = w_dst; i = (b - 5120) * 256 + threadIdx.x; }
  float4 v = reinterpret_cast<const float4*>(src)[i];
  ushort4 o;
  o.x = f2bf(v.x); o.y = f2bf(v.y); o.z = f2bf(v.z); o.w = f2bf(v.w);
  reinterpret_cast<ushort4*>(dst)[i] = o;
}

// ---------- 1024x1024 f32 -> bf16 transpose: dst[j][i] = src[i][j] ----------
__global__ __launch_bounds__(256) void transpose_bf16_kernel(const float* __restrict__ src,
                                                             u16* __restrict__ dst) {
  __shared__ float tile[32][33];
  int tx = threadIdx.x & 31, ty = threadIdx.x >> 5;  // 32 x 8
  int bx = blockIdx.x * 32, by = blockIdx.y * 32;
#pragma unroll
  for (int j = 0; j < 32; j += 8)
    tile[ty + j][tx] = src[(size_t)(by + ty + j) * 1024 + bx + tx];
  __syncthreads();
#pragma unroll
  for (int j = 0; j < 32; j += 8)
    dst[(size_t)(bx + ty + j) * 1024 + by + tx] = f2bf(tile[tx][ty + j]);
}

// ---------- stage 128 rows x 64 cols bf16 tile into linear LDS [128][64] ----------
// g must already point at (row0, k0). 256 threads, 4 issues of global_load_lds w=16.
// LDS dest is wave-uniform base + lane*16B (HW rule); chunk c lands at linear
// element offset 8c = row(c>>3)*64 + col((c&7)*8)  -> exact [128][64] row-major.
__device__ __forceinline__ void stage_tile(const u16* __restrict__ g, size_t row_stride,
                                           u16* lds, int tid) {
#pragma unroll
  for (int s = 0; s < 4; ++s) {
    int chunk = s * 256 + tid;                    // 16B chunk index, 1024 total
    const u16* gp = g + (size_t)(chunk >> 3) * row_stride + (size_t)((chunk & 7) * 8);
    u16* lp = lds + (tid >> 6) * 512 + s * 2048;  // wave-uniform base (elements)
    gload_lds16(gp, lp);
  }
}

// ---------- batched NT-GEMM 1024^3 bf16: C = A * B, Bt holds B^T row-major ----------
// Also writes C^T (for later use as an NT operand).
struct PowArgs {
  const u16* A[8];
  const u16* Bt[8];
  u16* C[8];
  u16* Ct[8];
};

__global__ __launch_bounds__(256) void pow_gemm_kernel(PowArgs args) {
  const u16* A  = args.A[blockIdx.z];
  const u16* Bt = args.Bt[blockIdx.z];
  u16* C  = args.C[blockIdx.z];
  u16* Ct = args.Ct[blockIdx.z];

  __shared__ __align__(16) u16 As[8192];
  __shared__ __align__(16) u16 Bs[8192];

  int tid = threadIdx.x;
  int lane = tid & 63, wave = tid >> 6;
  int wr = wave >> 1, wc = wave & 1;
  int lr = lane & 15, lg = lane >> 4;
  int m0 = blockIdx.x * 128, n0 = blockIdx.y * 128;

  f32x4 acc[4][4];
  const f32x4 zero = {0.f, 0.f, 0.f, 0.f};
#pragma unroll
  for (int m = 0; m < 4; ++m)
#pragma unroll
    for (int n = 0; n < 4; ++n) acc[m][n] = zero;

  for (int k0 = 0; k0 < 1024; k0 += 64) {
    stage_tile(A + (size_t)m0 * 1024 + k0, 1024, As, tid);
    stage_tile(Bt + (size_t)n0 * 1024 + k0, 1024, Bs, tid);
    __syncthreads();
#pragma unroll
    for (int ks = 0; ks < 2; ++ks) {
      bf16x8 a[4], b[4];
#pragma unroll
      for (int m = 0; m < 4; ++m)
        a[m] = *reinterpret_cast<const bf16x8*>(As + (wr * 64 + m * 16 + lr) * 64 + ks * 32 + lg * 8);
#pragma unroll
      for (int n = 0; n < 4; ++n)
        b[n] = *reinterpret_cast<const bf16x8*>(Bs + (wc * 64 + n * 16 + lr) * 64 + ks * 32 + lg * 8);
#pragma unroll
      for (int m = 0; m < 4; ++m)
#pragma unroll
        for (int n = 0; n < 4; ++n)
          acc[m][n] = __builtin_amdgcn_mfma_f32_16x16x32_bf16(a[m], b[n], acc[m][n], 0, 0, 0);
    }
    __syncthreads();
  }

#pragma unroll
  for (int m = 0; m < 4; ++m) {
    int row0 = m0 + wr * 64 + m * 16 + lg * 4;
#pragma unroll
    for (int n = 0; n < 4; ++n) {
      int col = n0 + wc * 64 + n * 16 + lr;
      f32x4 c = acc[m][n];
      ushort4 pk;
      pk.x = f2bf(c[0]); pk.y = f2bf(c[1]); pk.z = f2bf(c[2]); pk.w = f2bf(c[3]);
      C[(size_t)(row0 + 0) * 1024 + col] = pk.x;
      C[(size_t)(row0 + 1) * 1024 + col] = pk.y;
      C[(size_t)(row0 + 2) * 1024 + col] = pk.z;
      C[(size_t)(row0 + 3) * 1024 + col] = pk.w;
      *reinterpret_cast<ushort4*>(Ct + (size_t)col * 1024 + row0) = pk;  // C^T, 8B packed
    }
  }
}

// ---------- fused score GEMM: K=2048 concat (query|F_t  ++  topics_t|Ua) ----------
// C[b,h] = sum_j query[b,j]*F_t[h,j] + sum_e topics[b,t,e]*Ua[h,e]
// epilogue: scores_raw[b,t] += sum_h va[h]*tanh(C[b,h])   (atomic over 8 N-tiles)
__global__ __launch_bounds__(256) void score_gemm_kernel(
    const u16* __restrict__ query_bf, const u16* __restrict__ topics_bf,
    const u16* __restrict__ F_base, const u16* __restrict__ Ua_bf,
    const float* __restrict__ va_w, float* __restrict__ scores_raw) {
  __shared__ __align__(16) u16 As[8192];
  __shared__ __align__(16) u16 Bs[8192];
  __shared__ float sbuf[128];

  int tid = threadIdx.x;
  int lane = tid & 63, wave = tid >> 6;
  int wr = wave >> 1, wc = wave & 1;
  int lr = lane & 15, lg = lane >> 4;
  int m0 = blockIdx.x * 128, n0 = blockIdx.y * 128;
  int t = blockIdx.z;

  if (tid < 128) sbuf[tid] = 0.f;

  const u16* Ft = F_base + (size_t)t * (1024 * 1024);

  f32x4 acc[4][4];
  const f32x4 zero = {0.f, 0.f, 0.f, 0.f};
#pragma unroll
  for (int m = 0; m < 4; ++m)
#pragma unroll
    for (int n = 0; n < 4; ++n) acc[m][n] = zero;

  for (int k0 = 0; k0 < 2048; k0 += 64) {
    const u16* asrc; size_t astr;
    const u16* bsrc;
    if (k0 < 1024) {
      asrc = query_bf + (size_t)m0 * 1024 + k0; astr = 1024;
      bsrc = Ft + (size_t)n0 * 1024 + k0;
    } else {
      asrc = topics_bf + (size_t)m0 * 16384 + (size_t)t * 1024 + (size_t)(k0 - 1024); astr = 16384;
      bsrc = Ua_bf + (size_t)n0 * 1024 + (size_t)(k0 - 1024);
    }
    stage_tile(asrc, astr, As, tid);
    stage_tile(bsrc, 1024, Bs, tid);
    __syncthreads();
#pragma unroll
    for (int ks = 0; ks < 2; ++ks) {
      bf16x8 a[4], b[4];
#pragma unroll
      for (int m = 0; m < 4; ++m)
        a[m] = *reinterpret_cast<const bf16x8*>(As + (wr * 64 + m * 16 + lr) * 64 + ks * 32 + lg * 8);
#pragma unroll
      for (int n = 0; n < 4; ++n)
        b[n] = *reinterpret_cast<const bf16x8*>(Bs + (wc * 64 + n * 16 + lr) * 64 + ks * 32 + lg * 8);
#pragma unroll
      for (int m = 0; m < 4; ++m)
#pragma unroll
        for (int n = 0; n < 4; ++n)
          acc[m][n] = __builtin_amdgcn_mfma_f32_16x16x32_bf16(a[m], b[n], acc[m][n], 0, 0, 0);
    }
    __syncthreads();
  }

  // epilogue: tanh, weight by va[h], reduce rows
  float va_c[4];
#pragma unroll
  for (int n = 0; n < 4; ++n) va_c[n] = va_w[n0 + wc * 64 + n * 16 + lr];

#pragma unroll
  for (int m = 0; m < 4; ++m) {
    float rs[4] = {0.f, 0.f, 0.f, 0.f};
#pragma unroll
    for (int n = 0; n < 4; ++n) {
      f32x4 c = acc[m][n];
      rs[0] += va_c[n] * fast_tanh(c[0]);
      rs[1] += va_c[n] * fast_tanh(c[1]);
      rs[2] += va_c[n] * fast_tanh(c[2]);
      rs[3] += va_c[n] * fast_tanh(c[3]);
    }
#pragma unroll
    for (int j = 0; j < 4; ++j) {  // reduce across the 16 lanes sharing this row
      float v = rs[j];
      v += __shfl_xor(v, 1);
      v += __shfl_xor(v, 2);
      v += __shfl_xor(v, 4);
      v += __shfl_xor(v, 8);
      if (lr == 0) atomicAdd(&sbuf[wr * 64 + m * 16 + lg * 4 + j], v);
    }
  }
  __syncthreads();
  if (tid < 128) atomicAdd(&scores_raw[(size_t)(m0 + tid) * 16 + t], sbuf[tid]);
}

// ---------- softmax over T + mt = alpha . topics ----------
__global__ __launch_bounds__(256) void softmax_mt_kernel(
    const float* __restrict__ scores_raw, const float* __restrict__ cov,
    const float* __restrict__ topics, const float* __restrict__ va_b,
    float* __restrict__ mt, float* __restrict__ alphas) {
  int b = blockIdx.x;
  int tid = threadIdx.x;
  float vb = va_b[0];
  float e[16];
  float mx = -3.4e38f;
#pragma unroll
  for (int t = 0; t < 16; ++t) {
    float s = (scores_raw[b * 16 + t] + vb) * cov[b * 16 + t];
    e[t] = s;
    mx = fmaxf(mx, s);
  }
  float sum = 0.f;
#pragma unroll
  for (int t = 0; t < 16; ++t) { e[t] = __expf(e[t] - mx); sum += e[t]; }
  float inv = 1.f / sum;
  if (tid == 0) {
#pragma unroll
    for (int t = 0; t < 16; ++t) alphas[b * 16 + t] = e[t] * inv;
  }
  const float4* tp = reinterpret_cast<const float4*>(topics + (size_t)b * 16384);
  float4 accv = {0.f, 0.f, 0.f, 0.f};
#pragma unroll
  for (int t = 0; t < 16; ++t) {
    float4 v = tp[t * 256 + tid];
    float a = e[t] * inv;
    accv.x += a * v.x; accv.y += a * v.y; accv.z += a * v.z; accv.w += a * v.w;
  }
  reinterpret_cast<float4*>(mt + (size_t)b * 1024)[tid] = accv;
}

// ---------- host orchestration ----------
extern "C" void kernel_launch(void* const* d_in, const int* in_sizes, int n_in,
                              void* d_out, int out_size, void* d_ws, size_t ws_size,
                              hipStream_t stream) {
  (void)in_sizes; (void)n_in; (void)out_size; (void)ws_size;
  const float* query = (const float*)d_in[0];
  const float* topics = (const float*)d_in[1];
  const float* cov   = (const float*)d_in[2];
  const float* Ua    = (const float*)d_in[3];
  const float* Wa    = (const float*)d_in[4];
  const float* va_w  = (const float*)d_in[5];
  const float* va_b  = (const float*)d_in[6];

  float* mt = (float*)d_out;
  float* alphas = mt + (size_t)4096 * 1024;

  char* ws = (char*)d_ws;
  u16* topics_bf = (u16*)(ws);                                  // 128 MB
  u16* query_bf  = (u16*)(ws + (size_t)128 * 1024 * 1024);      // 8 MB
  u16* Ua_bf     = (u16*)(ws + (size_t)136 * 1024 * 1024);      // 2 MB
  u16* F_base    = (u16*)(ws + (size_t)138 * 1024 * 1024);      // 32 MB : F[i] = Wa^(i+1)
  u16* FT_base   = (u16*)(ws + (size_t)170 * 1024 * 1024);      // 32 MB : transposes
  float* scores_raw = (float*)(ws + (size_t)202 * 1024 * 1024); // 256 KB

  hipMemsetAsync(scores_raw, 0, (size_t)4096 * 16 * sizeof(float), stream);

  cvt_kernel<<<65536, 256, 0, stream>>>(topics, topics_bf, 16777216);
  cvt3_kernel<<<6144, 256, 0, stream>>>(query, query_bf, Ua, Ua_bf, Wa, F_base);
  transpose_bf16_kernel<<<dim3(32, 32), 256, 0, stream>>>(Wa, FT_base);

  const size_t MS = 1024 * 1024;
  auto F  = [&](int i) { return F_base + (size_t)i * MS; };
  auto FT = [&](int i) { return FT_base + (size_t)i * MS; };

  // log-depth power doubling: slot i holds Wa^(i+1)
  PowArgs a1{};
  a1.A[0] = F(0); a1.Bt[0] = FT(0); a1.C[0] = F(1); a1.Ct[0] = FT(1);            // Wa^2
  pow_gemm_kernel<<<dim3(8, 8, 1), 256, 0, stream>>>(a1);
  PowArgs a2{};
  a2.A[0] = F(1); a2.Bt[0] = FT(0); a2.C[0] = F(2); a2.Ct[0] = FT(2);            // Wa^3
  a2.A[1] = F(1); a2.Bt[1] = FT(1); a2.C[1] = F(3); a2.Ct[1] = FT(3);            // Wa^4
  pow_gemm_kernel<<<dim3(8, 8, 2), 256, 0, stream>>>(a2);
  PowArgs a3{};
  for (int p = 0; p < 4; ++p) { a3.A[p] = F(3); a3.Bt[p] = FT(p); a3.C[p] = F(4 + p); a3.Ct[p] = FT(4 + p); } // Wa^5..8
  pow_gemm_kernel<<<dim3(8, 8, 4), 256, 0, stream>>>(a3);
  PowArgs a4{};
  for (int p = 0; p < 8; ++p) { a4.A[p] = F(7); a4.Bt[p] = FT(p); a4.C[p] = F(8 + p); a4.Ct[p] = FT(8 + p); } // Wa^9..16
  pow_gemm_kernel<<<dim3(8, 8, 8), 256, 0, stream>>>(a4);

  score_gemm_kernel<<<dim3(32, 8, 16), 256, 0, stream>>>(query_bf, topics_bf, F_base, Ua_bf,
                                                         va_w, scores_raw);
  softmax_mt_kernel<<<4096, 256, 0, stream>>>(scores_raw, cov, topics, va_b, mt, alphas);
}

// Round 4
// 823.025 us; speedup vs baseline: 1.1081x; 1.1081x over previous
//
#include <hip/hip_runtime.h>

typedef unsigned short u16;
typedef unsigned int u32;
typedef __attribute__((ext_vector_type(8))) __bf16 bf16x8;
typedef __attribute__((ext_vector_type(4))) float f32x4;

// ---------- helpers ----------
__device__ __forceinline__ u16 f2bf(float f) {
  u32 u = __float_as_uint(f);
  u32 r = (u + 0x7FFFu + ((u >> 16) & 1u)) >> 16;  // RNE
  return (u16)r;
}

__device__ __forceinline__ void gload_lds16(const void* g, void* l) {
  __builtin_amdgcn_global_load_lds((const __attribute__((address_space(1))) u32*)g,
                                   (__attribute__((address_space(3))) u32*)l, 16, 0, 0);
}

__device__ __forceinline__ float fast_tanh(float x) {
  x = fminf(fmaxf(x, -15.f), 15.f);
  float e2 = __expf(2.f * x);
  return (e2 - 1.f) / (e2 + 1.f);
}

// ---------- fp32 -> bf16 convert (grid-stride, float4 granular) ----------
__global__ __launch_bounds__(256) void cvt_kernel(const float* __restrict__ src,
                                                  u16* __restrict__ dst, int n4) {
  int stride = gridDim.x * blockDim.x;
  for (int i = blockIdx.x * blockDim.x + threadIdx.x; i < n4; i += stride) {
    float4 v = reinterpret_cast<const float4*>(src)[i];
    ushort4 o;
    o.x = f2bf(v.x); o.y = f2bf(v.y); o.z = f2bf(v.z); o.w = f2bf(v.w);
    reinterpret_cast<ushort4*>(dst)[i] = o;
  }
}

// ---------- merged small converts: query (4096 blocks) | Ua (1024) | Wa (1024) ----------
__global__ __launch_bounds__(256) void cvt3_kernel(const float* __restrict__ q_src, u16* __restrict__ q_dst,
                                                   const float* __restrict__ u_src, u16* __restrict__ u_dst,
                                                   const float* __restrict__ w_src, u16* __restrict__ w_dst) {
  int b = blockIdx.x;
  const float* src; u16* dst; int i;
  if (b < 4096)      { src = q_src; dst = q_dst; i = b * 256 + threadIdx.x; }
  else if (b < 5120) { src = u_src; dst = u_dst; i = (b - 4096) * 256 + threadIdx.x; }
  else               { src = w_src; dst = w_dst; i = (b - 5120) * 256 + threadIdx.x; }
  float4 v = reinterpret_cast<const float4*>(src)[i];
  ushort4 o;
  o.x = f2bf(v.x); o.y = f2bf(v.y); o.z = f2bf(v.z); o.w = f2bf(v.w);
  reinterpret_cast<ushort4*>(dst)[i] = o;
}

// ---------- 1024x1024 f32 -> bf16 transpose: dst[j][i] = src[i][j] ----------
__global__ __launch_bounds__(256) void transpose_bf16_kernel(const float* __restrict__ src,
                                                             u16* __restrict__ dst) {
  __shared__ float tile[32][33];
  int tx = threadIdx.x & 31, ty = threadIdx.x >> 5;  // 32 x 8
  int bx = blockIdx.x * 32, by = blockIdx.y * 32;
#pragma unroll
  for (int j = 0; j < 32; j += 8)
    tile[ty + j][tx] = src[(size_t)(by + ty + j) * 1024 + bx + tx];
  __syncthreads();
#pragma unroll
  for (int j = 0; j < 32; j += 8)
    dst[(size_t)(bx + ty + j) * 1024 + by + tx] = f2bf(tile[tx][ty + j]);
}

// ---------- pow GEMM staging: 128x64 tile, XOR-swizzled source (T2, rule #21) ----------
// Physical chunk p holds logical chunk ((p&7) ^ ((p>>3)&7)) of row p>>3.
__device__ __forceinline__ void stage_tile(const u16* __restrict__ g, size_t row_stride,
                                           u16* lds, int tid) {
#pragma unroll
  for (int s = 0; s < 4; ++s) {
    int chunk = s * 256 + tid;                    // 16B chunk index, 1024 total
    int row = chunk >> 3;
    int kcl = (chunk & 7) ^ (row & 7);            // inverse-swizzled source chunk
    const u16* gp = g + (size_t)row * row_stride + (size_t)(kcl * 8);
    u16* lp = lds + (tid >> 6) * 512 + s * 2048;  // wave-uniform base (elements)
    gload_lds16(gp, lp);
  }
}

// ---------- batched NT-GEMM 1024^3 bf16 (2-phase, swizzled reads) ----------
struct PowArgs {
  const u16* A[8];
  const u16* Bt[8];
  u16* C[8];
  u16* Ct[8];
};

__global__ __launch_bounds__(256) void pow_gemm_kernel(PowArgs args) {
  const u16* A  = args.A[blockIdx.z];
  const u16* Bt = args.Bt[blockIdx.z];
  u16* C  = args.C[blockIdx.z];
  u16* Ct = args.Ct[blockIdx.z];

  __shared__ __align__(16) u16 As[8192];
  __shared__ __align__(16) u16 Bs[8192];

  int tid = threadIdx.x;
  int lane = tid & 63, wave = tid >> 6;
  int wr = wave >> 1, wc = wave & 1;
  int lr = lane & 15, lg = lane >> 4;
  int m0 = blockIdx.x * 128, n0 = blockIdx.y * 128;

  f32x4 acc[4][4];
  const f32x4 zero = {0.f, 0.f, 0.f, 0.f};
#pragma unroll
  for (int m = 0; m < 4; ++m)
#pragma unroll
    for (int n = 0; n < 4; ++n) acc[m][n] = zero;

  for (int k0 = 0; k0 < 1024; k0 += 64) {
    stage_tile(A + (size_t)m0 * 1024 + k0, 1024, As, tid);
    stage_tile(Bt + (size_t)n0 * 1024 + k0, 1024, Bs, tid);
    __syncthreads();
#pragma unroll
    for (int ks = 0; ks < 2; ++ks) {
      bf16x8 a[4], b[4];
#pragma unroll
      for (int m = 0; m < 4; ++m) {
        int ra = wr * 64 + m * 16 + lr;
        a[m] = *reinterpret_cast<const bf16x8*>(As + ra * 64 + (((ks * 4 + lg) ^ (ra & 7)) << 3));
      }
#pragma unroll
      for (int n = 0; n < 4; ++n) {
        int rb = wc * 64 + n * 16 + lr;
        b[n] = *reinterpret_cast<const bf16x8*>(Bs + rb * 64 + (((ks * 4 + lg) ^ (rb & 7)) << 3));
      }
#pragma unroll
      for (int m = 0; m < 4; ++m)
#pragma unroll
        for (int n = 0; n < 4; ++n)
          acc[m][n] = __builtin_amdgcn_mfma_f32_16x16x32_bf16(a[m], b[n], acc[m][n], 0, 0, 0);
    }
    __syncthreads();
  }

#pragma unroll
  for (int m = 0; m < 4; ++m) {
    int row0 = m0 + wr * 64 + m * 16 + lg * 4;
#pragma unroll
    for (int n = 0; n < 4; ++n) {
      int col = n0 + wc * 64 + n * 16 + lr;
      f32x4 c = acc[m][n];
      ushort4 pk;
      pk.x = f2bf(c[0]); pk.y = f2bf(c[1]); pk.z = f2bf(c[2]); pk.w = f2bf(c[3]);
      C[(size_t)(row0 + 0) * 1024 + col] = pk.x;
      C[(size_t)(row0 + 1) * 1024 + col] = pk.y;
      C[(size_t)(row0 + 2) * 1024 + col] = pk.z;
      C[(size_t)(row0 + 3) * 1024 + col] = pk.w;
      *reinterpret_cast<ushort4*>(Ct + (size_t)col * 1024 + row0) = pk;  // C^T
    }
  }
}

// =====================================================================
// score8: fused score GEMM, 256x256 tile, BK=64, 8 waves, 8-phase
// schedule (T2 swizzle + T3/T4 counted vmcnt + T5 setprio).
// C[b,h] = sum_j query[b,j]*F_t[h,j] + sum_e topics[b,t,e]*Ua[h,e]  (K=2048 concat)
// epilogue: scores_raw[b,t] += sum_h va[h]*tanh(C[b,h])
//
// LDS (dynamic 128KB): buf{0,1} x [Ak0|Ak1|Bk0|Bk1], region = [256 rows][32 cols]
// bf16 = 16KB. Region consumption: *k0 in {P0,P1}, *k1 in {P2,P3} -> stage
// schedule P0:(kt+1)Ak1  P1:(kt+1)Bk1  P2:(kt+2)Ak0  P3:(kt+2)Bk0 gives
// vmcnt(4) (2 regions in flight) at each tile boundary.
// =====================================================================

#define PHASE_READS(CUR, KS, MH)                                                 \
  { _Pragma("unroll") for (int i_ = 0; i_ < 4; ++i_) af[i_] = lda(CUR, KS, (MH)*4 + i_); \
    if ((MH) == 0) { _Pragma("unroll") for (int n_ = 0; n_ < 4; ++n_) bfr[n_] = ldb(CUR, KS, n_); } }

#define PHASE_MFMA(MH)                                                           \
  { __builtin_amdgcn_s_barrier();                                                \
    asm volatile("s_waitcnt lgkmcnt(0)" ::: "memory");                           \
    __builtin_amdgcn_sched_barrier(0);                                           \
    __builtin_amdgcn_s_setprio(1);                                               \
    _Pragma("unroll") for (int i_ = 0; i_ < 4; ++i_)                             \
      _Pragma("unroll") for (int n_ = 0; n_ < 4; ++n_)                           \
        acc[(MH)*4 + i_][n_] =                                                   \
            __builtin_amdgcn_mfma_f32_16x16x32_bf16(af[i_], bfr[n_], acc[(MH)*4 + i_][n_], 0, 0, 0); \
    __builtin_amdgcn_s_setprio(0); }

#define PHASE_END()                                                              \
  { __builtin_amdgcn_s_barrier(); __builtin_amdgcn_sched_barrier(0); }

__global__ __launch_bounds__(512, 2) void score8_kernel(
    const u16* __restrict__ query_bf, const u16* __restrict__ topics_bf,
    const u16* __restrict__ F_base, const u16* __restrict__ Ua_bf,
    const float* __restrict__ va_w, float* __restrict__ scores_raw) {
  extern __shared__ __align__(16) char lds[];

  const int tid = threadIdx.x;
  const int lane = tid & 63, wave = tid >> 6;
  const int wm = wave >> 2, wn = wave & 3;   // 2 x 4 wave grid
  const int lr = lane & 15, lg = lane >> 4;
  const int m0 = blockIdx.x * 256, n0 = blockIdx.y * 256;
  const int t = blockIdx.z;
  const int NT = 32;                          // K = 2048 = 32 tiles of 64

  const u16* Ft = F_base + (size_t)t * (1024 * 1024);

  // A/B source resolver per K-tile index (concat-K switch at tile 16)
  auto a_src = [&](int kt, const u16*& p, int& str) {
    if (kt < 16) { p = query_bf + (size_t)m0 * 1024 + kt * 64; str = 1024; }
    else { p = topics_bf + (size_t)m0 * 16384 + (size_t)t * 1024 + (kt - 16) * 64; str = 16384; }
  };
  auto b_src = [&](int kt, const u16*& p, int& str) {
    if (kt < 16) { p = Ft + (size_t)n0 * 1024 + kt * 64; str = 1024; }
    else { p = Ua_bf + (size_t)n0 * 1024 + (kt - 16) * 64; str = 1024; }
  };

  // stage one 16KB region [256 rows][32 cols]; linear LDS dest, inverse-swizzled
  // global source (chunk c' = c ^ ((row>>1)&3) within each 64B row).
  auto stage = [&](const u16* p, int str, int ks, int lds_byte) {
#pragma unroll
    for (int s = 0; s < 2; ++s) {
      int c = s * 512 + tid;
      int row = c >> 2;
      int cl = (c & 3) ^ ((row >> 1) & 3);
      const u16* gp = p + (size_t)row * str + ks * 32 + cl * 8;
      char* lp = lds + lds_byte + s * 8192 + (tid >> 6) * 1024;  // wave-uniform
      gload_lds16(gp, lp);
    }
  };

  // swizzled fragment reads (match the stage involution)
  auto lda = [&](int cur, int ks, int m) -> bf16x8 {
    int row = wm * 128 + m * 16 + lr;
    int byte = cur * 65536 + ks * 16384 + row * 64 + ((lg ^ ((row >> 1) & 3)) << 4);
    return *reinterpret_cast<const bf16x8*>(lds + byte);
  };
  auto ldb = [&](int cur, int ks, int n) -> bf16x8 {
    int row = wn * 64 + n * 16 + lr;
    int byte = cur * 65536 + 32768 + ks * 16384 + row * 64 + ((lg ^ ((row >> 1) & 3)) << 4);
    return *reinterpret_cast<const bf16x8*>(lds + byte);
  };

  f32x4 acc[8][4];
  const f32x4 zero = {0.f, 0.f, 0.f, 0.f};
#pragma unroll
  for (int m = 0; m < 8; ++m)
#pragma unroll
    for (int n = 0; n < 4; ++n) acc[m][n] = zero;

  bf16x8 af[4], bfr[4];
  const u16 *ap, *bp; int as_, bs_;

  // ---- prologue: tile0 all 4 regions + tile1 {Ak0,Bk0}; wait vmcnt(4) ----
  a_src(0, ap, as_); stage(ap, as_, 0, 0);              // (0) Ak0 -> buf0
  b_src(0, bp, bs_); stage(bp, bs_, 0, 32768);          // (0) Bk0
  a_src(0, ap, as_); stage(ap, as_, 1, 16384);          // (0) Ak1
  b_src(0, bp, bs_); stage(bp, bs_, 1, 49152);          // (0) Bk1
  a_src(1, ap, as_); stage(ap, as_, 0, 65536);          // (1) Ak0 -> buf1
  b_src(1, bp, bs_); stage(bp, bs_, 0, 65536 + 32768);  // (1) Bk0
  asm volatile("s_waitcnt vmcnt(4)" ::: "memory");
  __builtin_amdgcn_s_barrier();
  __builtin_amdgcn_sched_barrier(0);

  // ---- main loop: 4 phases per K-tile ----
#pragma unroll 2
  for (int kt = 0; kt < NT; ++kt) {
    int cur = kt & 1, nxt = cur ^ 1;
    // P0: mfma {m0-3, ks0}; stage (kt+1) Ak1 (buf nxt: free since kt-1 done)
    PHASE_READS(cur, 0, 0);
    if (kt + 1 < NT) { a_src(kt + 1, ap, as_); stage(ap, as_, 1, nxt * 65536 + 16384); }
    PHASE_MFMA(0); PHASE_END();
    // P1: mfma {m4-7, ks0}; stage (kt+1) Bk1
    PHASE_READS(cur, 0, 1);
    if (kt + 1 < NT) { b_src(kt + 1, bp, bs_); stage(bp, bs_, 1, nxt * 65536 + 49152); }
    PHASE_MFMA(1); PHASE_END();
    // P2: mfma {m0-3, ks1}; stage (kt+2) Ak0 (buf cur: Ak0 freed after P1)
    PHASE_READS(cur, 1, 0);
    if (kt + 2 < NT) { a_src(kt + 2, ap, as_); stage(ap, as_, 0, cur * 65536); }
    PHASE_MFMA(0); PHASE_END();
    // P3: mfma {m4-7, ks1}; stage (kt+2) Bk0 (freed after P1); tile-boundary wait
    PHASE_READS(cur, 1, 1);
    if (kt + 2 < NT) { b_src(kt + 2, bp, bs_); stage(bp, bs_, 0, cur * 65536 + 32768); }
    PHASE_MFMA(1);
    if (kt < NT - 2)       { asm volatile("s_waitcnt vmcnt(4)" ::: "memory"); }
    else if (kt == NT - 2) { asm volatile("s_waitcnt vmcnt(0)" ::: "memory"); }
    PHASE_END();
  }

  // ---- epilogue: tanh, va-weight, row-reduce; cross-wave sum via LDS reuse ----
  float va_c[4];
#pragma unroll
  for (int n = 0; n < 4; ++n) va_c[n] = va_w[n0 + wn * 64 + n * 16 + lr];

  float* sred = (float*)lds;  // all staging drained (vmcnt(0) at kt==NT-2), all waves past barrier
#pragma unroll
  for (int m = 0; m < 8; ++m) {
    float rs[4] = {0.f, 0.f, 0.f, 0.f};
#pragma unroll
    for (int n = 0; n < 4; ++n) {
      f32x4 c = acc[m][n];
      rs[0] += va_c[n] * fast_tanh(c[0]);
      rs[1] += va_c[n] * fast_tanh(c[1]);
      rs[2] += va_c[n] * fast_tanh(c[2]);
      rs[3] += va_c[n] * fast_tanh(c[3]);
    }
#pragma unroll
    for (int j = 0; j < 4; ++j) {  // reduce over the 16 lr lanes
      float v = rs[j];
      v += __shfl_xor(v, 1);
      v += __shfl_xor(v, 2);
      v += __shfl_xor(v, 4);
      v += __shfl_xor(v, 8);
      if (lr == 0) sred[wn * 256 + wm * 128 + m * 16 + lg * 4 + j] = v;
    }
  }
  __syncthreads();
  if (tid < 256) {
    float s = sred[tid] + sred[256 + tid] + sred[512 + tid] + sred[768 + tid];
    atomicAdd(&scores_raw[(size_t)(m0 + tid) * 16 + t], s);
  }
}

// ---------- softmax over T + mt = alpha . topics ----------
__global__ __launch_bounds__(256) void softmax_mt_kernel(
    const float* __restrict__ scores_raw, const float* __restrict__ cov,
    const float* __restrict__ topics, const float* __restrict__ va_b,
    float* __restrict__ mt, float* __restrict__ alphas) {
  int b = blockIdx.x;
  int tid = threadIdx.x;
  float vb = va_b[0];
  float e[16];
  float mx = -3.4e38f;
#pragma unroll
  for (int t = 0; t < 16; ++t) {
    float s = (scores_raw[b * 16 + t] + vb) * cov[b * 16 + t];
    e[t] = s;
    mx = fmaxf(mx, s);
  }
  float sum = 0.f;
#pragma unroll
  for (int t = 0; t < 16; ++t) { e[t] = __expf(e[t] - mx); sum += e[t]; }
  float inv = 1.f / sum;
  if (tid == 0) {
#pragma unroll
    for (int t = 0; t < 16; ++t) alphas[b * 16 + t] = e[t] * inv;
  }
  const float4* tp = reinterpret_cast<const float4*>(topics + (size_t)b * 16384);
  float4 accv = {0.f, 0.f, 0.f, 0.f};
#pragma unroll
  for (int t = 0; t < 16; ++t) {
    float4 v = tp[t * 256 + tid];
    float a = e[t] * inv;
    accv.x += a * v.x; accv.y += a * v.y; accv.z += a * v.z; accv.w += a * v.w;
  }
  reinterpret_cast<float4*>(mt + (size_t)b * 1024)[tid] = accv;
}

// ---------- host orchestration ----------
extern "C" void kernel_launch(void* const* d_in, const int* in_sizes, int n_in,
                              void* d_out, int out_size, void* d_ws, size_t ws_size,
                              hipStream_t stream) {
  (void)in_sizes; (void)n_in; (void)out_size; (void)ws_size;
  const float* query = (const float*)d_in[0];
  const float* topics = (const float*)d_in[1];
  const float* cov   = (const float*)d_in[2];
  const float* Ua    = (const float*)d_in[3];
  const float* Wa    = (const float*)d_in[4];
  const float* va_w  = (const float*)d_in[5];
  const float* va_b  = (const float*)d_in[6];

  float* mt = (float*)d_out;
  float* alphas = mt + (size_t)4096 * 1024;

  char* ws = (char*)d_ws;
  u16* topics_bf = (u16*)(ws);                                  // 128 MB
  u16* query_bf  = (u16*)(ws + (size_t)128 * 1024 * 1024);      // 8 MB
  u16* Ua_bf     = (u16*)(ws + (size_t)136 * 1024 * 1024);      // 2 MB
  u16* F_base    = (u16*)(ws + (size_t)138 * 1024 * 1024);      // 32 MB : F[i] = Wa^(i+1)
  u16* FT_base   = (u16*)(ws + (size_t)170 * 1024 * 1024);      // 32 MB : transposes
  float* scores_raw = (float*)(ws + (size_t)202 * 1024 * 1024); // 256 KB

  hipFuncSetAttribute(reinterpret_cast<const void*>(score8_kernel),
                      hipFuncAttributeMaxDynamicSharedMemorySize, 131072);

  hipMemsetAsync(scores_raw, 0, (size_t)4096 * 16 * sizeof(float), stream);

  cvt_kernel<<<8192, 256, 0, stream>>>(topics, topics_bf, 16777216);
  cvt3_kernel<<<6144, 256, 0, stream>>>(query, query_bf, Ua, Ua_bf, Wa, F_base);
  transpose_bf16_kernel<<<dim3(32, 32), 256, 0, stream>>>(Wa, FT_base);

  const size_t MS = 1024 * 1024;
  auto F  = [&](int i) { return F_base + (size_t)i * MS; };
  auto FT = [&](int i) { return FT_base + (size_t)i * MS; };

  // log-depth power doubling: slot i holds Wa^(i+1)
  PowArgs a1{};
  a1.A[0] = F(0); a1.Bt[0] = FT(0); a1.C[0] = F(1); a1.Ct[0] = FT(1);            // Wa^2
  pow_gemm_kernel<<<dim3(8, 8, 1), 256, 0, stream>>>(a1);
  PowArgs a2{};
  a2.A[0] = F(1); a2.Bt[0] = FT(0); a2.C[0] = F(2); a2.Ct[0] = FT(2);            // Wa^3
  a2.A[1] = F(1); a2.Bt[1] = FT(1); a2.C[1] = F(3); a2.Ct[1] = FT(3);            // Wa^4
  pow_gemm_kernel<<<dim3(8, 8, 2), 256, 0, stream>>>(a2);
  PowArgs a3{};
  for (int p = 0; p < 4; ++p) { a3.A[p] = F(3); a3.Bt[p] = FT(p); a3.C[p] = F(4 + p); a3.Ct[p] = FT(4 + p); } // Wa^5..8
  pow_gemm_kernel<<<dim3(8, 8, 4), 256, 0, stream>>>(a3);
  PowArgs a4{};
  for (int p = 0; p < 8; ++p) { a4.A[p] = F(7); a4.Bt[p] = FT(p); a4.C[p] = F(8 + p); a4.Ct[p] = FT(8 + p); } // Wa^9..16
  pow_gemm_kernel<<<dim3(8, 8, 8), 256, 0, stream>>>(a4);

  score8_kernel<<<dim3(16, 4, 16), 512, 131072, stream>>>(query_bf, topics_bf, F_base, Ua_bf,
                                                          va_w, scores_raw);
  softmax_mt_kernel<<<4096, 256, 0, stream>>>(scores_raw, cov, topics, va_b, mt, alphas);
}

// Round 6
// 817.839 us; speedup vs baseline: 1.1152x; 1.0063x over previous
//
#include <hip/hip_runtime.h>

typedef unsigned short u16;
typedef unsigned int u32;
typedef __attribute__((ext_vector_type(8))) __bf16 bf16x8;
typedef __attribute__((ext_vector_type(4))) float f32x4;

// ---------- helpers ----------
__device__ __forceinline__ u16 f2bf(float f) {
  u32 u = __float_as_uint(f);
  u32 r = (u + 0x7FFFu + ((u >> 16) & 1u)) >> 16;  // RNE
  return (u16)r;
}

__device__ __forceinline__ void gload_lds16(const void* g, void* l) {
  __builtin_amdgcn_global_load_lds((const __attribute__((address_space(1))) u32*)g,
                                   (__attribute__((address_space(3))) u32*)l, 16, 0, 0);
}

__device__ __forceinline__ float fast_tanh(float x) {
  x = fminf(fmaxf(x, -15.f), 15.f);
  float e2 = __expf(2.f * x);
  return (e2 - 1.f) / (e2 + 1.f);
}

// ---------- fp32 -> bf16 convert (grid-stride, float4 granular) ----------
__global__ __launch_bounds__(256) void cvt_kernel(const float* __restrict__ src,
                                                  u16* __restrict__ dst, int n4) {
  int stride = gridDim.x * blockDim.x;
  for (int i = blockIdx.x * blockDim.x + threadIdx.x; i < n4; i += stride) {
    float4 v = reinterpret_cast<const float4*>(src)[i];
    ushort4 o;
    o.x = f2bf(v.x); o.y = f2bf(v.y); o.z = f2bf(v.z); o.w = f2bf(v.w);
    reinterpret_cast<ushort4*>(dst)[i] = o;
  }
}

// ---------- merged small converts: query (4096 blocks) | Ua (1024) | Wa (1024) ----------
__global__ __launch_bounds__(256) void cvt3_kernel(const float* __restrict__ q_src, u16* __restrict__ q_dst,
                                                   const float* __restrict__ u_src, u16* __restrict__ u_dst,
                                                   const float* __restrict__ w_src, u16* __restrict__ w_dst) {
  int b = blockIdx.x;
  const float* src; u16* dst; int i;
  if (b < 4096)      { src = q_src; dst = q_dst; i = b * 256 + threadIdx.x; }
  else if (b < 5120) { src = u_src; dst = u_dst; i = (b - 4096) * 256 + threadIdx.x; }
  else               { src = w_src; dst = w_dst; i = (b - 5120) * 256 + threadIdx.x; }
  float4 v = reinterpret_cast<const float4*>(src)[i];
  ushort4 o;
  o.x = f2bf(v.x); o.y = f2bf(v.y); o.z = f2bf(v.z); o.w = f2bf(v.w);
  reinterpret_cast<ushort4*>(dst)[i] = o;
}

// ---------- 1024x1024 f32 -> bf16 transpose: dst[j][i] = src[i][j] ----------
__global__ __launch_bounds__(256) void transpose_bf16_kernel(const float* __restrict__ src,
                                                             u16* __restrict__ dst) {
  __shared__ float tile[32][33];
  int tx = threadIdx.x & 31, ty = threadIdx.x >> 5;  // 32 x 8
  int bx = blockIdx.x * 32, by = blockIdx.y * 32;
#pragma unroll
  for (int j = 0; j < 32; j += 8)
    tile[ty + j][tx] = src[(size_t)(by + ty + j) * 1024 + bx + tx];
  __syncthreads();
#pragma unroll
  for (int j = 0; j < 32; j += 8)
    dst[(size_t)(bx + ty + j) * 1024 + by + tx] = f2bf(tile[tx][ty + j]);
}

// ---------- pow GEMM staging: 128x64 tile, XOR-swizzled source (T2, rule #21) ----------
__device__ __forceinline__ void stage_tile(const u16* __restrict__ g, size_t row_stride,
                                           u16* lds, int tid) {
#pragma unroll
  for (int s = 0; s < 4; ++s) {
    int chunk = s * 256 + tid;                    // 16B chunk index, 1024 total
    int row = chunk >> 3;
    int kcl = (chunk & 7) ^ (row & 7);            // inverse-swizzled source chunk
    const u16* gp = g + (size_t)row * row_stride + (size_t)(kcl * 8);
    u16* lp = lds + (tid >> 6) * 512 + s * 2048;  // wave-uniform base (elements)
    gload_lds16(gp, lp);
  }
}

// ---------- batched NT-GEMM 1024^3 bf16 (2-phase, swizzled reads) ----------
struct PowArgs {
  const u16* A[8];
  const u16* Bt[8];
  u16* C[8];
  u16* Ct[8];
};

__global__ __launch_bounds__(256) void pow_gemm_kernel(PowArgs args) {
  const u16* A  = args.A[blockIdx.z];
  const u16* Bt = args.Bt[blockIdx.z];
  u16* C  = args.C[blockIdx.z];
  u16* Ct = args.Ct[blockIdx.z];

  __shared__ __align__(16) u16 As[8192];
  __shared__ __align__(16) u16 Bs[8192];

  int tid = threadIdx.x;
  int lane = tid & 63, wave = tid >> 6;
  int wr = wave >> 1, wc = wave & 1;
  int lr = lane & 15, lg = lane >> 4;
  int m0 = blockIdx.x * 128, n0 = blockIdx.y * 128;

  f32x4 acc[4][4];
  const f32x4 zero = {0.f, 0.f, 0.f, 0.f};
#pragma unroll
  for (int m = 0; m < 4; ++m)
#pragma unroll
    for (int n = 0; n < 4; ++n) acc[m][n] = zero;

  for (int k0 = 0; k0 < 1024; k0 += 64) {
    stage_tile(A + (size_t)m0 * 1024 + k0, 1024, As, tid);
    stage_tile(Bt + (size_t)n0 * 1024 + k0, 1024, Bs, tid);
    __syncthreads();
#pragma unroll
    for (int ks = 0; ks < 2; ++ks) {
      bf16x8 a[4], b[4];
#pragma unroll
      for (int m = 0; m < 4; ++m) {
        int ra = wr * 64 + m * 16 + lr;
        a[m] = *reinterpret_cast<const bf16x8*>(As + ra * 64 + (((ks * 4 + lg) ^ (ra & 7)) << 3));
      }
#pragma unroll
      for (int n = 0; n < 4; ++n) {
        int rb = wc * 64 + n * 16 + lr;
        b[n] = *reinterpret_cast<const bf16x8*>(Bs + rb * 64 + (((ks * 4 + lg) ^ (rb & 7)) << 3));
      }
#pragma unroll
      for (int m = 0; m < 4; ++m)
#pragma unroll
        for (int n = 0; n < 4; ++n)
          acc[m][n] = __builtin_amdgcn_mfma_f32_16x16x32_bf16(a[m], b[n], acc[m][n], 0, 0, 0);
    }
    __syncthreads();
  }

#pragma unroll
  for (int m = 0; m < 4; ++m) {
    int row0 = m0 + wr * 64 + m * 16 + lg * 4;
#pragma unroll
    for (int n = 0; n < 4; ++n) {
      int col = n0 + wc * 64 + n * 16 + lr;
      f32x4 c = acc[m][n];
      ushort4 pk;
      pk.x = f2bf(c[0]); pk.y = f2bf(c[1]); pk.z = f2bf(c[2]); pk.w = f2bf(c[3]);
      C[(size_t)(row0 + 0) * 1024 + col] = pk.x;
      C[(size_t)(row0 + 1) * 1024 + col] = pk.y;
      C[(size_t)(row0 + 2) * 1024 + col] = pk.z;
      C[(size_t)(row0 + 3) * 1024 + col] = pk.w;
      *reinterpret_cast<ushort4*>(Ct + (size_t)col * 1024 + row0) = pk;  // C^T
    }
  }
}

// ---------- 64^2-tile variant for the small early power steps (fills the grid) ----------
__device__ __forceinline__ void stage_tile64(const u16* __restrict__ g, u16* lds, int tid) {
#pragma unroll
  for (int s = 0; s < 2; ++s) {
    int chunk = s * 256 + tid;                    // 512 chunks: 64 rows x 8
    int row = chunk >> 3;
    int kcl = (chunk & 7) ^ (row & 7);
    const u16* gp = g + (size_t)row * 1024 + (size_t)(kcl * 8);
    u16* lp = lds + (tid >> 6) * 512 + s * 2048;  // wave-uniform
    gload_lds16(gp, lp);
  }
}

__global__ __launch_bounds__(256) void pow64_gemm_kernel(PowArgs args) {
  const u16* A  = args.A[blockIdx.z];
  const u16* Bt = args.Bt[blockIdx.z];
  u16* C  = args.C[blockIdx.z];
  u16* Ct = args.Ct[blockIdx.z];

  __shared__ __align__(16) u16 As[4096];
  __shared__ __align__(16) u16 Bs[4096];

  int tid = threadIdx.x;
  int lane = tid & 63, wave = tid >> 6;
  int wr = wave >> 1, wc = wave & 1;
  int lr = lane & 15, lg = lane >> 4;
  int m0 = blockIdx.x * 64, n0 = blockIdx.y * 64;

  f32x4 acc[2][2];
  const f32x4 zero = {0.f, 0.f, 0.f, 0.f};
#pragma unroll
  for (int m = 0; m < 2; ++m)
#pragma unroll
    for (int n = 0; n < 2; ++n) acc[m][n] = zero;

  for (int k0 = 0; k0 < 1024; k0 += 64) {
    stage_tile64(A + (size_t)m0 * 1024 + k0, As, tid);
    stage_tile64(Bt + (size_t)n0 * 1024 + k0, Bs, tid);
    __syncthreads();
#pragma unroll
    for (int ks = 0; ks < 2; ++ks) {
      bf16x8 a[2], b[2];
#pragma unroll
      for (int m = 0; m < 2; ++m) {
        int ra = wr * 32 + m * 16 + lr;
        a[m] = *reinterpret_cast<const bf16x8*>(As + ra * 64 + (((ks * 4 + lg) ^ (ra & 7)) << 3));
      }
#pragma unroll
      for (int n = 0; n < 2; ++n) {
        int rb = wc * 32 + n * 16 + lr;
        b[n] = *reinterpret_cast<const bf16x8*>(Bs + rb * 64 + (((ks * 4 + lg) ^ (rb & 7)) << 3));
      }
#pragma unroll
      for (int m = 0; m < 2; ++m)
#pragma unroll
        for (int n = 0; n < 2; ++n)
          acc[m][n] = __builtin_amdgcn_mfma_f32_16x16x32_bf16(a[m], b[n], acc[m][n], 0, 0, 0);
    }
    __syncthreads();
  }

#pragma unroll
  for (int m = 0; m < 2; ++m) {
    int row0 = m0 + wr * 32 + m * 16 + lg * 4;
#pragma unroll
    for (int n = 0; n < 2; ++n) {
      int col = n0 + wc * 32 + n * 16 + lr;
      f32x4 c = acc[m][n];
      ushort4 pk;
      pk.x = f2bf(c[0]); pk.y = f2bf(c[1]); pk.z = f2bf(c[2]); pk.w = f2bf(c[3]);
      C[(size_t)(row0 + 0) * 1024 + col] = pk.x;
      C[(size_t)(row0 + 1) * 1024 + col] = pk.y;
      C[(size_t)(row0 + 2) * 1024 + col] = pk.z;
      C[(size_t)(row0 + 3) * 1024 + col] = pk.w;
      *reinterpret_cast<ushort4*>(Ct + (size_t)col * 1024 + row0) = pk;
    }
  }
}

// =====================================================================
// score8: fused score GEMM, 256x256 tile, BK=64, 8 waves, 8-phase
// schedule. Zero per-phase VALU for ds_reads (precomputed per-thread
// bases + compile-time offset:imm) and ~4-op stage calls.
//
// LDS 128KB: A at [0,64K): [buf][ks][16KB]; B at [64K,128K): [buf][ks][16KB].
// Region = [256 rows][32 cols] bf16, XOR-swizzled (involution c^=(row>>1)&3
// on 16B chunks within 64B rows), applied on stage-source AND read.
// Stage schedule per tile kt: P0:(kt+1)A.ks1  P1:(kt+1)B.ks1
// P2:(kt+2)A.ks0  P3:(kt+2)B.ks0; vmcnt(4) at P3 -> tile kt+1 fully
// landed, 2 regions (kt+2 ks0) in flight. Prologue 12 loads, vmcnt(4).
// =====================================================================

#define PHASE_READS(CUR, KS, MH)                                                     \
  { _Pragma("unroll") for (int i_ = 0; i_ < 4; ++i_)                                 \
      af[i_] = *reinterpret_cast<const bf16x8*>(lds + aoffv[(MH)*4 + i_] +           \
                                                (CUR)*32768 + (KS)*16384);           \
    if ((MH) == 0) { _Pragma("unroll") for (int n_ = 0; n_ < 4; ++n_)                \
      bfr[n_] = *reinterpret_cast<const bf16x8*>(lds + boffv[n_] +                   \
                                                 (CUR)*32768 + (KS)*16384); } }

#define PHASE_MFMA(MH)                                                               \
  { __builtin_amdgcn_s_barrier();                                                    \
    asm volatile("s_waitcnt lgkmcnt(0)" ::: "memory");                               \
    __builtin_amdgcn_sched_barrier(0);                                               \
    __builtin_amdgcn_s_setprio(1);                                                   \
    _Pragma("unroll") for (int i_ = 0; i_ < 4; ++i_)                                 \
      _Pragma("unroll") for (int n_ = 0; n_ < 4; ++n_)                               \
        acc[(MH)*4 + i_][n_] =                                                       \
            __builtin_amdgcn_mfma_f32_16x16x32_bf16(af[i_], bfr[n_], acc[(MH)*4 + i_][n_], 0, 0, 0); \
    __builtin_amdgcn_s_setprio(0); }

#define PHASE_END()                                                                  \
  { __builtin_amdgcn_s_barrier(); __builtin_amdgcn_sched_barrier(0); }

__global__ __launch_bounds__(512, 2) void score8_kernel(
    const u16* __restrict__ query_bf, const u16* __restrict__ topics_bf,
    const u16* __restrict__ F_base, const u16* __restrict__ Ua_bf,
    const float* __restrict__ va_w, float* __restrict__ scores_raw) {
  extern __shared__ __align__(16) char lds[];

  const int tid = threadIdx.x;
  const int lane = tid & 63, wave = tid >> 6;
  const int wm = wave >> 2, wn = wave & 3;   // 2 x 4 wave grid
  const int lr = lane & 15, lg = lane >> 4;
  const int m0 = blockIdx.x * 256, n0 = blockIdx.y * 256;
  const int t = blockIdx.z;
  const int NT = 32;                          // K = 2048 = 32 tiles of 64

  const u16* Ft = F_base + (size_t)t * (1024 * 1024);

  // --- precomputed per-thread ds_read byte offsets within a region ---
  u32 aoffv[8], boffv[4];
#pragma unroll
  for (int m = 0; m < 8; ++m) {
    int row = wm * 128 + m * 16 + lr;
    aoffv[m] = row * 64 + ((lg ^ ((row >> 1) & 3)) << 4);
  }
#pragma unroll
  for (int n = 0; n < 4; ++n) {
    int row = wn * 64 + n * 16 + lr;
    boffv[n] = 65536 + row * 64 + ((lg ^ ((row >> 1) & 3)) << 4);
  }

  // --- precomputed per-thread staging source offsets (elements) ---
  u32 goff1[2], goff2[2];
#pragma unroll
  for (int s = 0; s < 2; ++s) {
    int c = s * 512 + tid;
    int row = c >> 2;
    int cl = (c & 3) ^ ((row >> 1) & 3);      // inverse swizzle on source
    goff1[s] = row * 1024 + cl * 8;           // stride-1024 sources
    goff2[s] = row * 16384 + cl * 8;          // topics (stride 16384)
  }
  char* sdst = lds + (tid >> 6) * 1024;       // wave-uniform LDS dest base
  const u16* qbase = query_bf + (size_t)m0 * 1024;
  const u16* tbase = topics_bf + (size_t)m0 * 16384 + (size_t)t * 1024 - 1024;
  const u16* fbase = Ft + (size_t)n0 * 1024;
  const u16* ubase = Ua_bf + (size_t)n0 * 1024 - 1024;

  auto stageA = [&](int kt, int ks, int buf) {
    const u16* base = (kt < 16 ? qbase : tbase) + kt * 64 + ks * 32;
#pragma unroll
    for (int s = 0; s < 2; ++s) {
      u32 off = (kt < 16) ? goff1[s] : goff2[s];
      gload_lds16(base + off, sdst + buf * 32768 + ks * 16384 + s * 8192);
    }
  };
  auto stageB = [&](int kt, int ks, int buf) {
    const u16* base = (kt < 16 ? fbase : ubase) + kt * 64 + ks * 32;
#pragma unroll
    for (int s = 0; s < 2; ++s)
      gload_lds16(base + goff1[s], sdst + 65536 + buf * 32768 + ks * 16384 + s * 8192);
  };

  f32x4 acc[8][4];
  const f32x4 zero = {0.f, 0.f, 0.f, 0.f};
#pragma unroll
  for (int m = 0; m < 8; ++m)
#pragma unroll
    for (int n = 0; n < 4; ++n) acc[m][n] = zero;

  bf16x8 af[4], bfr[4];

  // ---- prologue: tile0 all regions + tile1 ks0; wait vmcnt(4) ----
  stageA(0, 0, 0); stageB(0, 0, 0);
  stageA(0, 1, 0); stageB(0, 1, 0);
  stageA(1, 0, 1); stageB(1, 0, 1);
  asm volatile("s_waitcnt vmcnt(4)" ::: "memory");
  __builtin_amdgcn_s_barrier();
  __builtin_amdgcn_sched_barrier(0);

  // ---- main loop: 4 phases per K-tile ----
#pragma unroll 2
  for (int kt = 0; kt < NT; ++kt) {
    int cur = kt & 1, nxt = cur ^ 1;
    // P0: mfma {m0-3, ks0}; stage (kt+1) A.ks1
    PHASE_READS(cur, 0, 0);
    if (kt + 1 < NT) stageA(kt + 1, 1, nxt);
    PHASE_MFMA(0); PHASE_END();
    // P1: mfma {m4-7, ks0}; stage (kt+1) B.ks1
    PHASE_READS(cur, 0, 1);
    if (kt + 1 < NT) stageB(kt + 1, 1, nxt);
    PHASE_MFMA(1); PHASE_END();
    // P2: mfma {m0-3, ks1}; stage (kt+2) A.ks0 (A[cur].ks0 freed at P1 lgkm)
    PHASE_READS(cur, 1, 0);
    if (kt + 2 < NT) stageA(kt + 2, 0, cur);
    PHASE_MFMA(0); PHASE_END();
    // P3: mfma {m4-7, ks1}; stage (kt+2) B.ks0; tile-boundary counted wait
    PHASE_READS(cur, 1, 1);
    if (kt + 2 < NT) stageB(kt + 2, 0, cur);
    PHASE_MFMA(1);
    if (kt < NT - 2)       { asm volatile("s_waitcnt vmcnt(4)" ::: "memory"); }
    else if (kt == NT - 2) { asm volatile("s_waitcnt vmcnt(0)" ::: "memory"); }
    PHASE_END();
  }

  // ---- epilogue: tanh, va-weight, row-reduce; cross-wave sum via LDS reuse ----
  float va_c[4];
#pragma unroll
  for (int n = 0; n < 4; ++n) va_c[n] = va_w[n0 + wn * 64 + n * 16 + lr];

  float* sred = (float*)lds;  // staging fully drained; all waves past final barrier
#pragma unroll
  for (int m = 0; m < 8; ++m) {
    float rs[4] = {0.f, 0.f, 0.f, 0.f};
#pragma unroll
    for (int n = 0; n < 4; ++n) {
      f32x4 c = acc[m][n];
      rs[0] += va_c[n] * fast_tanh(c[0]);
      rs[1] += va_c[n] * fast_tanh(c[1]);
      rs[2] += va_c[n] * fast_tanh(c[2]);
      rs[3] += va_c[n] * fast_tanh(c[3]);
    }
#pragma unroll
    for (int j = 0; j < 4; ++j) {  // reduce over the 16 lr lanes
      float v = rs[j];
      v += __shfl_xor(v, 1);
      v += __shfl_xor(v, 2);
      v += __shfl_xor(v, 4);
      v += __shfl_xor(v, 8);
      if (lr == 0) sred[wn * 256 + wm * 128 + m * 16 + lg * 4 + j] = v;
    }
  }
  __syncthreads();
  if (tid < 256) {
    float s = sred[tid] + sred[256 + tid] + sred[512 + tid] + sred[768 + tid];
    atomicAdd(&scores_raw[(size_t)(m0 + tid) * 16 + t], s);
  }
}

// ---------- softmax over T + mt = alpha . topics ----------
__global__ __launch_bounds__(256) void softmax_mt_kernel(
    const float* __restrict__ scores_raw, const float* __restrict__ cov,
    const float* __restrict__ topics, const float* __restrict__ va_b,
    float* __restrict__ mt, float* __restrict__ alphas) {
  int b = blockIdx.x;
  int tid = threadIdx.x;
  float vb = va_b[0];
  float e[16];
  float mx = -3.4e38f;
#pragma unroll
  for (int t = 0; t < 16; ++t) {
    float s = (scores_raw[b * 16 + t] + vb) * cov[b * 16 + t];
    e[t] = s;
    mx = fmaxf(mx, s);
  }
  float sum = 0.f;
#pragma unroll
  for (int t = 0; t < 16; ++t) { e[t] = __expf(e[t] - mx); sum += e[t]; }
  float inv = 1.f / sum;
  if (tid == 0) {
#pragma unroll
    for (int t = 0; t < 16; ++t) alphas[b * 16 + t] = e[t] * inv;
  }
  const float4* tp = reinterpret_cast<const float4*>(topics + (size_t)b * 16384);
  float4 accv = {0.f, 0.f, 0.f, 0.f};
#pragma unroll
  for (int t = 0; t < 16; ++t) {
    float4 v = tp[t * 256 + tid];
    float a = e[t] * inv;
    accv.x += a * v.x; accv.y += a * v.y; accv.z += a * v.z; accv.w += a * v.w;
  }
  reinterpret_cast<float4*>(mt + (size_t)b * 1024)[tid] = accv;
}

// ---------- host orchestration ----------
extern "C" void kernel_launch(void* const* d_in, const int* in_sizes, int n_in,
                              void* d_out, int out_size, void* d_ws, size_t ws_size,
                              hipStream_t stream) {
  (void)in_sizes; (void)n_in; (void)out_size; (void)ws_size;
  const float* query = (const float*)d_in[0];
  const float* topics = (const float*)d_in[1];
  const float* cov   = (const float*)d_in[2];
  const float* Ua    = (const float*)d_in[3];
  const float* Wa    = (const float*)d_in[4];
  const float* va_w  = (const float*)d_in[5];
  const float* va_b  = (const float*)d_in[6];

  float* mt = (float*)d_out;
  float* alphas = mt + (size_t)4096 * 1024;

  char* ws = (char*)d_ws;
  u16* topics_bf = (u16*)(ws);                                  // 128 MB
  u16* query_bf  = (u16*)(ws + (size_t)128 * 1024 * 1024);      // 8 MB
  u16* Ua_bf     = (u16*)(ws + (size_t)136 * 1024 * 1024);      // 2 MB
  u16* F_base    = (u16*)(ws + (size_t)138 * 1024 * 1024);      // 32 MB : F[i] = Wa^(i+1)
  u16* FT_base   = (u16*)(ws + (size_t)170 * 1024 * 1024);      // 32 MB : transposes
  float* scores_raw = (float*)(ws + (size_t)202 * 1024 * 1024); // 256 KB

  hipFuncSetAttribute(reinterpret_cast<const void*>(score8_kernel),
                      hipFuncAttributeMaxDynamicSharedMemorySize, 131072);

  hipMemsetAsync(scores_raw, 0, (size_t)4096 * 16 * sizeof(float), stream);

  cvt_kernel<<<8192, 256, 0, stream>>>(topics, topics_bf, 16777216);
  cvt3_kernel<<<6144, 256, 0, stream>>>(query, query_bf, Ua, Ua_bf, Wa, F_base);
  transpose_bf16_kernel<<<dim3(32, 32), 256, 0, stream>>>(Wa, FT_base);

  const size_t MS = 1024 * 1024;
  auto F  = [&](int i) { return F_base + (size_t)i * MS; };
  auto FT = [&](int i) { return FT_base + (size_t)i * MS; };

  // log-depth power doubling: slot i holds Wa^(i+1)
  PowArgs a1{};
  a1.A[0] = F(0); a1.Bt[0] = FT(0); a1.C[0] = F(1); a1.Ct[0] = FT(1);            // Wa^2
  pow64_gemm_kernel<<<dim3(16, 16, 1), 256, 0, stream>>>(a1);
  PowArgs a2{};
  a2.A[0] = F(1); a2.Bt[0] = FT(0); a2.C[0] = F(2); a2.Ct[0] = FT(2);            // Wa^3
  a2.A[1] = F(1); a2.Bt[1] = FT(1); a2.C[1] = F(3); a2.Ct[1] = FT(3);            // Wa^4
  pow64_gemm_kernel<<<dim3(16, 16, 2), 256, 0, stream>>>(a2);
  PowArgs a3{};
  for (int p = 0; p < 4; ++p) { a3.A[p] = F(3); a3.Bt[p] = FT(p); a3.C[p] = F(4 + p); a3.Ct[p] = FT(4 + p); } // Wa^5..8
  pow_gemm_kernel<<<dim3(8, 8, 4), 256, 0, stream>>>(a3);
  PowArgs a4{};
  for (int p = 0; p < 8; ++p) { a4.A[p] = F(7); a4.Bt[p] = FT(p); a4.C[p] = F(8 + p); a4.Ct[p] = FT(8 + p); } // Wa^9..16
  pow_gemm_kernel<<<dim3(8, 8, 8), 256, 0, stream>>>(a4);

  score8_kernel<<<dim3(16, 4, 16), 512, 131072, stream>>>(query_bf, topics_bf, F_base, Ua_bf,
                                                          va_w, scores_raw);
  softmax_mt_kernel<<<4096, 256, 0, stream>>>(scores_raw, cov, topics, va_b, mt, alphas);
}

// Round 7
// 817.603 us; speedup vs baseline: 1.1155x; 1.0003x over previous
//
#include <hip/hip_runtime.h>

typedef unsigned short u16;
typedef unsigned int u32;
typedef __attribute__((ext_vector_type(8))) __bf16 bf16x8;
typedef __attribute__((ext_vector_type(4))) float f32x4;

// ---------- helpers ----------
__device__ __forceinline__ u16 f2bf(float f) {
  u32 u = __float_as_uint(f);
  u32 r = (u + 0x7FFFu + ((u >> 16) & 1u)) >> 16;  // RNE
  return (u16)r;
}

__device__ __forceinline__ void gload_lds16(const void* g, void* l) {
  __builtin_amdgcn_global_load_lds((const __attribute__((address_space(1))) u32*)g,
                                   (__attribute__((address_space(3))) u32*)l, 16, 0, 0);
}

__device__ __forceinline__ float fast_tanh(float x) {
  x = fminf(fmaxf(x, -15.f), 15.f);
  float e2 = __expf(2.f * x);
  return (e2 - 1.f) / (e2 + 1.f);
}

// ---------- fp32 -> bf16 convert (grid-stride, float4 granular) ----------
__global__ __launch_bounds__(256) void cvt_kernel(const float* __restrict__ src,
                                                  u16* __restrict__ dst, int n4) {
  int stride = gridDim.x * blockDim.x;
  for (int i = blockIdx.x * blockDim.x + threadIdx.x; i < n4; i += stride) {
    float4 v = reinterpret_cast<const float4*>(src)[i];
    ushort4 o;
    o.x = f2bf(v.x); o.y = f2bf(v.y); o.z = f2bf(v.z); o.w = f2bf(v.w);
    reinterpret_cast<ushort4*>(dst)[i] = o;
  }
}

// ---------- merged: query|Ua|Wa converts + Wa transpose (one dispatch) ----------
__global__ __launch_bounds__(256) void cvt3t_kernel(const float* __restrict__ q_src, u16* __restrict__ q_dst,
                                                    const float* __restrict__ u_src, u16* __restrict__ u_dst,
                                                    const float* __restrict__ w_src, u16* __restrict__ w_dst,
                                                    u16* __restrict__ wt_dst) {
  __shared__ float tile[32][33];
  int b = blockIdx.x;
  if (b < 6144) {
    const float* src; u16* dst; int i;
    if (b < 4096)      { src = q_src; dst = q_dst; i = b * 256 + threadIdx.x; }
    else if (b < 5120) { src = u_src; dst = u_dst; i = (b - 4096) * 256 + threadIdx.x; }
    else               { src = w_src; dst = w_dst; i = (b - 5120) * 256 + threadIdx.x; }
    float4 v = reinterpret_cast<const float4*>(src)[i];
    ushort4 o;
    o.x = f2bf(v.x); o.y = f2bf(v.y); o.z = f2bf(v.z); o.w = f2bf(v.w);
    reinterpret_cast<ushort4*>(dst)[i] = o;
  } else {
    int tb = b - 6144;                     // 1024 transpose blocks: 32 x 32
    int tx = threadIdx.x & 31, ty = threadIdx.x >> 5;  // 32 x 8
    int bx = (tb & 31) * 32, by = (tb >> 5) * 32;
#pragma unroll
    for (int j = 0; j < 32; j += 8)
      tile[ty + j][tx] = w_src[(size_t)(by + ty + j) * 1024 + bx + tx];
    __syncthreads();
#pragma unroll
    for (int j = 0; j < 32; j += 8)
      wt_dst[(size_t)(bx + ty + j) * 1024 + by + tx] = f2bf(tile[tx][ty + j]);
  }
}

// ---------- pow GEMM staging: 128x64 tile, XOR-swizzled source (T2, rule #21) ----------
__device__ __forceinline__ void stage_tile(const u16* __restrict__ g, size_t row_stride,
                                           u16* lds, int tid) {
#pragma unroll
  for (int s = 0; s < 4; ++s) {
    int chunk = s * 256 + tid;                    // 16B chunk index, 1024 total
    int row = chunk >> 3;
    int kcl = (chunk & 7) ^ (row & 7);            // inverse-swizzled source chunk
    const u16* gp = g + (size_t)row * row_stride + (size_t)(kcl * 8);
    u16* lp = lds + (tid >> 6) * 512 + s * 2048;  // wave-uniform base (elements)
    gload_lds16(gp, lp);
  }
}

// ---------- batched NT-GEMM 1024^3 bf16 (2-phase, swizzled reads) ----------
struct PowArgs {
  const u16* A[8];
  const u16* Bt[8];
  u16* C[8];
  u16* Ct[8];
};

__global__ __launch_bounds__(256) void pow_gemm_kernel(PowArgs args) {
  const u16* A  = args.A[blockIdx.z];
  const u16* Bt = args.Bt[blockIdx.z];
  u16* C  = args.C[blockIdx.z];
  u16* Ct = args.Ct[blockIdx.z];

  __shared__ __align__(16) u16 As[8192];
  __shared__ __align__(16) u16 Bs[8192];

  int tid = threadIdx.x;
  int lane = tid & 63, wave = tid >> 6;
  int wr = wave >> 1, wc = wave & 1;
  int lr = lane & 15, lg = lane >> 4;
  int m0 = blockIdx.x * 128, n0 = blockIdx.y * 128;

  f32x4 acc[4][4];
  const f32x4 zero = {0.f, 0.f, 0.f, 0.f};
#pragma unroll
  for (int m = 0; m < 4; ++m)
#pragma unroll
    for (int n = 0; n < 4; ++n) acc[m][n] = zero;

  for (int k0 = 0; k0 < 1024; k0 += 64) {
    stage_tile(A + (size_t)m0 * 1024 + k0, 1024, As, tid);
    stage_tile(Bt + (size_t)n0 * 1024 + k0, 1024, Bs, tid);
    __syncthreads();
#pragma unroll
    for (int ks = 0; ks < 2; ++ks) {
      bf16x8 a[4], b[4];
#pragma unroll
      for (int m = 0; m < 4; ++m) {
        int ra = wr * 64 + m * 16 + lr;
        a[m] = *reinterpret_cast<const bf16x8*>(As + ra * 64 + (((ks * 4 + lg) ^ (ra & 7)) << 3));
      }
#pragma unroll
      for (int n = 0; n < 4; ++n) {
        int rb = wc * 64 + n * 16 + lr;
        b[n] = *reinterpret_cast<const bf16x8*>(Bs + rb * 64 + (((ks * 4 + lg) ^ (rb & 7)) << 3));
      }
#pragma unroll
      for (int m = 0; m < 4; ++m)
#pragma unroll
        for (int n = 0; n < 4; ++n)
          acc[m][n] = __builtin_amdgcn_mfma_f32_16x16x32_bf16(a[m], b[n], acc[m][n], 0, 0, 0);
    }
    __syncthreads();
  }

#pragma unroll
  for (int m = 0; m < 4; ++m) {
    int row0 = m0 + wr * 64 + m * 16 + lg * 4;
#pragma unroll
    for (int n = 0; n < 4; ++n) {
      int col = n0 + wc * 64 + n * 16 + lr;
      f32x4 c = acc[m][n];
      ushort4 pk;
      pk.x = f2bf(c[0]); pk.y = f2bf(c[1]); pk.z = f2bf(c[2]); pk.w = f2bf(c[3]);
      C[(size_t)(row0 + 0) * 1024 + col] = pk.x;
      C[(size_t)(row0 + 1) * 1024 + col] = pk.y;
      C[(size_t)(row0 + 2) * 1024 + col] = pk.z;
      C[(size_t)(row0 + 3) * 1024 + col] = pk.w;
      *reinterpret_cast<ushort4*>(Ct + (size_t)col * 1024 + row0) = pk;  // C^T
    }
  }
}

// ---------- 64^2-tile variant for the small early power steps (fills the grid) ----------
__device__ __forceinline__ void stage_tile64(const u16* __restrict__ g, u16* lds, int tid) {
#pragma unroll
  for (int s = 0; s < 2; ++s) {
    int chunk = s * 256 + tid;                    // 512 chunks: 64 rows x 8
    int row = chunk >> 3;
    int kcl = (chunk & 7) ^ (row & 7);
    const u16* gp = g + (size_t)row * 1024 + (size_t)(kcl * 8);
    u16* lp = lds + (tid >> 6) * 512 + s * 2048;  // wave-uniform
    gload_lds16(gp, lp);
  }
}

__global__ __launch_bounds__(256) void pow64_gemm_kernel(PowArgs args) {
  const u16* A  = args.A[blockIdx.z];
  const u16* Bt = args.Bt[blockIdx.z];
  u16* C  = args.C[blockIdx.z];
  u16* Ct = args.Ct[blockIdx.z];

  __shared__ __align__(16) u16 As[4096];
  __shared__ __align__(16) u16 Bs[4096];

  int tid = threadIdx.x;
  int lane = tid & 63, wave = tid >> 6;
  int wr = wave >> 1, wc = wave & 1;
  int lr = lane & 15, lg = lane >> 4;
  int m0 = blockIdx.x * 64, n0 = blockIdx.y * 64;

  f32x4 acc[2][2];
  const f32x4 zero = {0.f, 0.f, 0.f, 0.f};
#pragma unroll
  for (int m = 0; m < 2; ++m)
#pragma unroll
    for (int n = 0; n < 2; ++n) acc[m][n] = zero;

  for (int k0 = 0; k0 < 1024; k0 += 64) {
    stage_tile64(A + (size_t)m0 * 1024 + k0, As, tid);
    stage_tile64(Bt + (size_t)n0 * 1024 + k0, Bs, tid);
    __syncthreads();
#pragma unroll
    for (int ks = 0; ks < 2; ++ks) {
      bf16x8 a[2], b[2];
#pragma unroll
      for (int m = 0; m < 2; ++m) {
        int ra = wr * 32 + m * 16 + lr;
        a[m] = *reinterpret_cast<const bf16x8*>(As + ra * 64 + (((ks * 4 + lg) ^ (ra & 7)) << 3));
      }
#pragma unroll
      for (int n = 0; n < 2; ++n) {
        int rb = wc * 32 + n * 16 + lr;
        b[n] = *reinterpret_cast<const bf16x8*>(Bs + rb * 64 + (((ks * 4 + lg) ^ (rb & 7)) << 3));
      }
#pragma unroll
      for (int m = 0; m < 2; ++m)
#pragma unroll
        for (int n = 0; n < 2; ++n)
          acc[m][n] = __builtin_amdgcn_mfma_f32_16x16x32_bf16(a[m], b[n], acc[m][n], 0, 0, 0);
    }
    __syncthreads();
  }

#pragma unroll
  for (int m = 0; m < 2; ++m) {
    int row0 = m0 + wr * 32 + m * 16 + lg * 4;
#pragma unroll
    for (int n = 0; n < 2; ++n) {
      int col = n0 + wc * 32 + n * 16 + lr;
      f32x4 c = acc[m][n];
      ushort4 pk;
      pk.x = f2bf(c[0]); pk.y = f2bf(c[1]); pk.z = f2bf(c[2]); pk.w = f2bf(c[3]);
      C[(size_t)(row0 + 0) * 1024 + col] = pk.x;
      C[(size_t)(row0 + 1) * 1024 + col] = pk.y;
      C[(size_t)(row0 + 2) * 1024 + col] = pk.z;
      C[(size_t)(row0 + 3) * 1024 + col] = pk.w;
      *reinterpret_cast<ushort4*>(Ct + (size_t)col * 1024 + row0) = pk;
    }
  }
}

// =====================================================================
// score8: fused score GEMM, 256x256 tile, BK=64, 8 waves.
// THIS ROUND: merged phases — 2 phases per K-tile, 32 MFMA per phase
// (barrier count halved vs round 5); XCD-grouped 1-D grid; per-y
// partial score output (no memset, no atomics).
//
// LDS 128KB: A at [0,64K): [buf][ks][16KB]; B at [64K,128K): same.
// Region [256 rows][32 cols] bf16, XOR-swizzled (c ^= (row>>1)&3 on 16B
// chunks within 64B rows) on stage-source AND read (involution).
//
// Schedule per tile kt (cur=kt&1, nxt=cur^1):
//  Q0: read A[cur].ks0 (8xb128) + B[cur].ks0 (4); issue stage (kt+1).ks1->nxt
//      (A+B, 4 loads); barrier; lgkmcnt(0); 32 MFMA ks0; barrier.
//  Q1: read *.ks1; issue stage (kt+2).ks0->cur (safe: cur.ks0 last read Q0,
//      stage issued after Q0's end barrier); 32 MFMA ks1; vmcnt(4); barrier.
// vmcnt invariant at tile start: 4 loads in flight = (kt+1).ks0. Q0 +4 -> 8,
// Q1 +4 -> 12, vmcnt(4) retires 8 = tile kt+1 complete; 4 remain. Prologue:
// 12 loads (tile0 full + tile1.ks0), vmcnt(4) => tile0 landed. Tail kt=NT-2:
// vmcnt(0) drains (tile NT-1 landed; epilogue LDS reuse safe).
// =====================================================================

#define QPHASE(CUR, KS, STAGE_STMT, WAIT_STMT)                                        \
  { _Pragma("unroll") for (int m_ = 0; m_ < 8; ++m_)                                  \
      af[m_] = *reinterpret_cast<const bf16x8*>(lds + aoffv[m_] +                     \
                                                (CUR)*32768 + (KS)*16384);            \
    _Pragma("unroll") for (int n_ = 0; n_ < 4; ++n_)                                  \
      bfr[n_] = *reinterpret_cast<const bf16x8*>(lds + boffv[n_] +                    \
                                                 (CUR)*32768 + (KS)*16384);           \
    STAGE_STMT;                                                                       \
    __builtin_amdgcn_s_barrier();                                                     \
    asm volatile("s_waitcnt lgkmcnt(0)" ::: "memory");                                \
    __builtin_amdgcn_sched_barrier(0);                                                \
    __builtin_amdgcn_s_setprio(1);                                                    \
    _Pragma("unroll") for (int m_ = 0; m_ < 8; ++m_)                                  \
      _Pragma("unroll") for (int n_ = 0; n_ < 4; ++n_)                                \
        acc[m_][n_] =                                                                 \
            __builtin_amdgcn_mfma_f32_16x16x32_bf16(af[m_], bfr[n_], acc[m_][n_], 0, 0, 0); \
    __builtin_amdgcn_s_setprio(0);                                                    \
    WAIT_STMT;                                                                        \
    __builtin_amdgcn_s_barrier();                                                     \
    __builtin_amdgcn_sched_barrier(0); }

__global__ __launch_bounds__(512, 2) void score8_kernel(
    const u16* __restrict__ query_bf, const u16* __restrict__ topics_bf,
    const u16* __restrict__ F_base, const u16* __restrict__ Ua_bf,
    const float* __restrict__ va_w, float* __restrict__ scores_part) {
  extern __shared__ __align__(16) char lds[];

  const int tid = threadIdx.x;
  const int lane = tid & 63, wave = tid >> 6;
  const int wm = wave >> 2, wn = wave & 3;   // 2 x 4 wave grid
  const int lr = lane & 15, lg = lane >> 4;

  // XCD-grouped decode: consecutive HW ids (round-robin across 8 XCDs) map to
  // far-apart logical ids so each XCD owns a contiguous logical chunk of 128
  // blocks = 2 full t-slices (all x,y). Bijective: 1024 % 8 == 0.
  const int bid = blockIdx.x;
  const int lid = (bid & 7) * 128 + (bid >> 3);
  const int x = lid & 15, y = (lid >> 4) & 3, t = lid >> 6;
  const int m0 = x * 256, n0 = y * 256;
  const int NT = 32;                          // K = 2048 = 32 tiles of 64

  const u16* Ft = F_base + (size_t)t * (1024 * 1024);

  // --- precomputed per-thread ds_read byte offsets within a region ---
  u32 aoffv[8], boffv[4];
#pragma unroll
  for (int m = 0; m < 8; ++m) {
    int row = wm * 128 + m * 16 + lr;
    aoffv[m] = row * 64 + ((lg ^ ((row >> 1) & 3)) << 4);
  }
#pragma unroll
  for (int n = 0; n < 4; ++n) {
    int row = wn * 64 + n * 16 + lr;
    boffv[n] = 65536 + row * 64 + ((lg ^ ((row >> 1) & 3)) << 4);
  }

  // --- precomputed per-thread staging source offsets (elements) ---
  u32 goff1[2], goff2[2];
#pragma unroll
  for (int s = 0; s < 2; ++s) {
    int c = s * 512 + tid;
    int row = c >> 2;
    int cl = (c & 3) ^ ((row >> 1) & 3);      // inverse swizzle on source
    goff1[s] = row * 1024 + cl * 8;           // stride-1024 sources
    goff2[s] = row * 16384 + cl * 8;          // topics (stride 16384)
  }
  char* sdst = lds + (tid >> 6) * 1024;       // wave-uniform LDS dest base
  const u16* qbase = query_bf + (size_t)m0 * 1024;
  const u16* tbase = topics_bf + (size_t)m0 * 16384 + (size_t)t * 1024 - 1024;
  const u16* fbase = Ft + (size_t)n0 * 1024;
  const u16* ubase = Ua_bf + (size_t)n0 * 1024 - 1024;

  auto stageA = [&](int kt, int ks, int buf) {
    const u16* base = (kt < 16 ? qbase : tbase) + kt * 64 + ks * 32;
#pragma unroll
    for (int s = 0; s < 2; ++s) {
      u32 off = (kt < 16) ? goff1[s] : goff2[s];
      gload_lds16(base + off, sdst + buf * 32768 + ks * 16384 + s * 8192);
    }
  };
  auto stageB = [&](int kt, int ks, int buf) {
    const u16* base = (kt < 16 ? fbase : ubase) + kt * 64 + ks * 32;
#pragma unroll
    for (int s = 0; s < 2; ++s)
      gload_lds16(base + goff1[s], sdst + 65536 + buf * 32768 + ks * 16384 + s * 8192);
  };

  f32x4 acc[8][4];
  const f32x4 zero = {0.f, 0.f, 0.f, 0.f};
#pragma unroll
  for (int m = 0; m < 8; ++m)
#pragma unroll
    for (int n = 0; n < 4; ++n) acc[m][n] = zero;

  bf16x8 af[8], bfr[4];

  // ---- prologue: tile0 full + tile1 ks0 (12 loads); vmcnt(4) => tile0 landed ----
  stageA(0, 0, 0); stageB(0, 0, 0);
  stageA(0, 1, 0); stageB(0, 1, 0);
  stageA(1, 0, 1); stageB(1, 0, 1);
  asm volatile("s_waitcnt vmcnt(4)" ::: "memory");
  __builtin_amdgcn_s_barrier();
  __builtin_amdgcn_sched_barrier(0);

  // ---- main loop: 2 merged phases per K-tile ----
#pragma unroll 2
  for (int kt = 0; kt < NT; ++kt) {
    int cur = kt & 1, nxt = cur ^ 1;
    QPHASE(cur, 0,
           { if (kt + 1 < NT) { stageA(kt + 1, 1, nxt); stageB(kt + 1, 1, nxt); } },
           {});
    QPHASE(cur, 1,
           { if (kt + 2 < NT) { stageA(kt + 2, 0, cur); stageB(kt + 2, 0, cur); } },
           { if (kt < NT - 2)       { asm volatile("s_waitcnt vmcnt(4)" ::: "memory"); }
             else if (kt == NT - 2) { asm volatile("s_waitcnt vmcnt(0)" ::: "memory"); } });
  }

  // ---- epilogue: tanh, va-weight, row-reduce; per-y partial (no atomics) ----
  float va_c[4];
#pragma unroll
  for (int n = 0; n < 4; ++n) va_c[n] = va_w[n0 + wn * 64 + n * 16 + lr];

  float* sred = (float*)lds;  // staging fully drained; all waves past final barrier
#pragma unroll
  for (int m = 0; m < 8; ++m) {
    float rs[4] = {0.f, 0.f, 0.f, 0.f};
#pragma unroll
    for (int n = 0; n < 4; ++n) {
      f32x4 c = acc[m][n];
      rs[0] += va_c[n] * fast_tanh(c[0]);
      rs[1] += va_c[n] * fast_tanh(c[1]);
      rs[2] += va_c[n] * fast_tanh(c[2]);
      rs[3] += va_c[n] * fast_tanh(c[3]);
    }
#pragma unroll
    for (int j = 0; j < 4; ++j) {  // reduce over the 16 lr lanes
      float v = rs[j];
      v += __shfl_xor(v, 1);
      v += __shfl_xor(v, 2);
      v += __shfl_xor(v, 4);
      v += __shfl_xor(v, 8);
      if (lr == 0) sred[wn * 256 + wm * 128 + m * 16 + lg * 4 + j] = v;
    }
  }
  __syncthreads();
  if (tid < 256) {
    float s = sred[tid] + sred[256 + tid] + sred[512 + tid] + sred[768 + tid];
    scores_part[((size_t)y * 4096 + m0 + tid) * 16 + t] = s;   // unique slot per block
  }
}

// ---------- softmax over T + mt = alpha . topics ----------
__global__ __launch_bounds__(256) void softmax_mt_kernel(
    const float* __restrict__ scores_part, const float* __restrict__ cov,
    const float* __restrict__ topics, const float* __restrict__ va_b,
    float* __restrict__ mt, float* __restrict__ alphas) {
  int b = blockIdx.x;
  int tid = threadIdx.x;
  float vb = va_b[0];
  float e[16];
  float mx = -3.4e38f;
#pragma unroll
  for (int t = 0; t < 16; ++t) {
    float s = 0.f;
#pragma unroll
    for (int yy = 0; yy < 4; ++yy) s += scores_part[((size_t)yy * 4096 + b) * 16 + t];
    s = (s + vb) * cov[b * 16 + t];
    e[t] = s;
    mx = fmaxf(mx, s);
  }
  float sum = 0.f;
#pragma unroll
  for (int t = 0; t < 16; ++t) { e[t] = __expf(e[t] - mx); sum += e[t]; }
  float inv = 1.f / sum;
  if (tid == 0) {
#pragma unroll
    for (int t = 0; t < 16; ++t) alphas[b * 16 + t] = e[t] * inv;
  }
  const float4* tp = reinterpret_cast<const float4*>(topics + (size_t)b * 16384);
  float4 accv = {0.f, 0.f, 0.f, 0.f};
#pragma unroll
  for (int t = 0; t < 16; ++t) {
    float4 v = tp[t * 256 + tid];
    float a = e[t] * inv;
    accv.x += a * v.x; accv.y += a * v.y; accv.z += a * v.z; accv.w += a * v.w;
  }
  reinterpret_cast<float4*>(mt + (size_t)b * 1024)[tid] = accv;
}

// ---------- host orchestration ----------
extern "C" void kernel_launch(void* const* d_in, const int* in_sizes, int n_in,
                              void* d_out, int out_size, void* d_ws, size_t ws_size,
                              hipStream_t stream) {
  (void)in_sizes; (void)n_in; (void)out_size; (void)ws_size;
  const float* query = (const float*)d_in[0];
  const float* topics = (const float*)d_in[1];
  const float* cov   = (const float*)d_in[2];
  const float* Ua    = (const float*)d_in[3];
  const float* Wa    = (const float*)d_in[4];
  const float* va_w  = (const float*)d_in[5];
  const float* va_b  = (const float*)d_in[6];

  float* mt = (float*)d_out;
  float* alphas = mt + (size_t)4096 * 1024;

  char* ws = (char*)d_ws;
  u16* topics_bf = (u16*)(ws);                                  // 128 MB
  u16* query_bf  = (u16*)(ws + (size_t)128 * 1024 * 1024);      // 8 MB
  u16* Ua_bf     = (u16*)(ws + (size_t)136 * 1024 * 1024);      // 2 MB
  u16* F_base    = (u16*)(ws + (size_t)138 * 1024 * 1024);      // 32 MB : F[i] = Wa^(i+1)
  u16* FT_base   = (u16*)(ws + (size_t)170 * 1024 * 1024);      // 32 MB : transposes
  float* scores_part = (float*)(ws + (size_t)202 * 1024 * 1024); // 4 MB [y][b][t]

  hipFuncSetAttribute(reinterpret_cast<const void*>(score8_kernel),
                      hipFuncAttributeMaxDynamicSharedMemorySize, 131072);

  cvt_kernel<<<8192, 256, 0, stream>>>(topics, topics_bf, 16777216);
  cvt3t_kernel<<<7168, 256, 0, stream>>>(query, query_bf, Ua, Ua_bf, Wa, F_base, FT_base);

  const size_t MS = 1024 * 1024;
  auto F  = [&](int i) { return F_base + (size_t)i * MS; };
  auto FT = [&](int i) { return FT_base + (size_t)i * MS; };

  // log-depth power doubling: slot i holds Wa^(i+1)
  PowArgs a1{};
  a1.A[0] = F(0); a1.Bt[0] = FT(0); a1.C[0] = F(1); a1.Ct[0] = FT(1);            // Wa^2
  pow64_gemm_kernel<<<dim3(16, 16, 1), 256, 0, stream>>>(a1);
  PowArgs a2{};
  a2.A[0] = F(1); a2.Bt[0] = FT(0); a2.C[0] = F(2); a2.Ct[0] = FT(2);            // Wa^3
  a2.A[1] = F(1); a2.Bt[1] = FT(1); a2.C[1] = F(3); a2.Ct[1] = FT(3);            // Wa^4
  pow64_gemm_kernel<<<dim3(16, 16, 2), 256, 0, stream>>>(a2);
  PowArgs a3{};
  for (int p = 0; p < 4; ++p) { a3.A[p] = F(3); a3.Bt[p] = FT(p); a3.C[p] = F(4 + p); a3.Ct[p] = FT(4 + p); } // Wa^5..8
  pow_gemm_kernel<<<dim3(8, 8, 4), 256, 0, stream>>>(a3);
  PowArgs a4{};
  for (int p = 0; p < 8; ++p) { a4.A[p] = F(7); a4.Bt[p] = FT(p); a4.C[p] = F(8 + p); a4.Ct[p] = FT(8 + p); } // Wa^9..16
  pow_gemm_kernel<<<dim3(8, 8, 8), 256, 0, stream>>>(a4);

  score8_kernel<<<1024, 512, 131072, stream>>>(query_bf, topics_bf, F_base, Ua_bf,
                                               va_w, scores_part);
  softmax_mt_kernel<<<4096, 256, 0, stream>>>(scores_part, cov, topics, va_b, mt, alphas);
}

// Round 8
// 792.167 us; speedup vs baseline: 1.1513x; 1.0321x over previous
//
#include <hip/hip_runtime.h>

typedef unsigned short u16;
typedef unsigned int u32;
typedef __attribute__((ext_vector_type(8))) __bf16 bf16x8;
typedef __attribute__((ext_vector_type(4))) float f32x4;

// ---------- helpers ----------
__device__ __forceinline__ u16 f2bf(float f) {
  u32 u = __float_as_uint(f);
  u32 r = (u + 0x7FFFu + ((u >> 16) & 1u)) >> 16;  // RNE
  return (u16)r;
}

__device__ __forceinline__ void gload_lds16(const void* g, void* l) {
  __builtin_amdgcn_global_load_lds((const __attribute__((address_space(1))) u32*)g,
                                   (__attribute__((address_space(3))) u32*)l, 16, 0, 0);
}

__device__ __forceinline__ float fast_tanh(float x) {
  x = fminf(fmaxf(x, -15.f), 15.f);
  float e2 = __expf(2.f * x);
  return (e2 - 1.f) / (e2 + 1.f);
}

// ---------- merged converts: topics | query | Ua | Wa | Wa^T (one dispatch) ----------
__global__ __launch_bounds__(256) void cvtall_kernel(
    const float* __restrict__ topics, u16* __restrict__ topics_bf,
    const float* __restrict__ q_src, u16* __restrict__ q_dst,
    const float* __restrict__ u_src, u16* __restrict__ u_dst,
    const float* __restrict__ w_src, u16* __restrict__ w_dst,
    u16* __restrict__ wt_dst) {
  __shared__ float tile[32][33];
  int b = blockIdx.x;
  if (b < 8192) {                              // topics: grid-stride over 16.7M float4
    for (int i = b * 256 + threadIdx.x; i < 16777216; i += 8192 * 256) {
      float4 v = reinterpret_cast<const float4*>(topics)[i];
      ushort4 o;
      o.x = f2bf(v.x); o.y = f2bf(v.y); o.z = f2bf(v.z); o.w = f2bf(v.w);
      reinterpret_cast<ushort4*>(topics_bf)[i] = o;
    }
  } else if (b < 14336) {                      // query | Ua | Wa straight converts
    const float* src; u16* dst; int i;
    if (b < 12288)      { src = q_src; dst = q_dst; i = (b - 8192) * 256 + threadIdx.x; }
    else if (b < 13312) { src = u_src; dst = u_dst; i = (b - 12288) * 256 + threadIdx.x; }
    else                { src = w_src; dst = w_dst; i = (b - 13312) * 256 + threadIdx.x; }
    float4 v = reinterpret_cast<const float4*>(src)[i];
    ushort4 o;
    o.x = f2bf(v.x); o.y = f2bf(v.y); o.z = f2bf(v.z); o.w = f2bf(v.w);
    reinterpret_cast<ushort4*>(dst)[i] = o;
  } else {                                     // Wa transpose (1024 blocks of 32x32)
    int tb = b - 14336;
    int tx = threadIdx.x & 31, ty = threadIdx.x >> 5;  // 32 x 8
    int bx = (tb & 31) * 32, by = (tb >> 5) * 32;
#pragma unroll
    for (int j = 0; j < 32; j += 8)
      tile[ty + j][tx] = w_src[(size_t)(by + ty + j) * 1024 + bx + tx];
    __syncthreads();
#pragma unroll
    for (int j = 0; j < 32; j += 8)
      wt_dst[(size_t)(bx + ty + j) * 1024 + by + tx] = f2bf(tile[tx][ty + j]);
  }
}

// ---------- pow GEMM staging: 128x64 tile, XOR-swizzled source (T2, rule #21) ----------
__device__ __forceinline__ void stage_tile(const u16* __restrict__ g, size_t row_stride,
                                           u16* lds, int tid) {
#pragma unroll
  for (int s = 0; s < 4; ++s) {
    int chunk = s * 256 + tid;                    // 16B chunk index, 1024 total
    int row = chunk >> 3;
    int kcl = (chunk & 7) ^ (row & 7);            // inverse-swizzled source chunk
    const u16* gp = g + (size_t)row * row_stride + (size_t)(kcl * 8);
    u16* lp = lds + (tid >> 6) * 512 + s * 2048;  // wave-uniform base (elements)
    gload_lds16(gp, lp);
  }
}

// ---------- batched NT-GEMM 1024^3 bf16 (2-phase, swizzled reads) ----------
struct PowArgs {
  const u16* A[8];
  const u16* Bt[8];
  u16* C[8];
  u16* Ct[8];
};

__global__ __launch_bounds__(256) void pow_gemm_kernel(PowArgs args) {
  const u16* A  = args.A[blockIdx.z];
  const u16* Bt = args.Bt[blockIdx.z];
  u16* C  = args.C[blockIdx.z];
  u16* Ct = args.Ct[blockIdx.z];

  __shared__ __align__(16) u16 As[8192];
  __shared__ __align__(16) u16 Bs[8192];

  int tid = threadIdx.x;
  int lane = tid & 63, wave = tid >> 6;
  int wr = wave >> 1, wc = wave & 1;
  int lr = lane & 15, lg = lane >> 4;
  int m0 = blockIdx.x * 128, n0 = blockIdx.y * 128;

  f32x4 acc[4][4];
  const f32x4 zero = {0.f, 0.f, 0.f, 0.f};
#pragma unroll
  for (int m = 0; m < 4; ++m)
#pragma unroll
    for (int n = 0; n < 4; ++n) acc[m][n] = zero;

  for (int k0 = 0; k0 < 1024; k0 += 64) {
    stage_tile(A + (size_t)m0 * 1024 + k0, 1024, As, tid);
    stage_tile(Bt + (size_t)n0 * 1024 + k0, 1024, Bs, tid);
    __syncthreads();
#pragma unroll
    for (int ks = 0; ks < 2; ++ks) {
      bf16x8 a[4], b[4];
#pragma unroll
      for (int m = 0; m < 4; ++m) {
        int ra = wr * 64 + m * 16 + lr;
        a[m] = *reinterpret_cast<const bf16x8*>(As + ra * 64 + (((ks * 4 + lg) ^ (ra & 7)) << 3));
      }
#pragma unroll
      for (int n = 0; n < 4; ++n) {
        int rb = wc * 64 + n * 16 + lr;
        b[n] = *reinterpret_cast<const bf16x8*>(Bs + rb * 64 + (((ks * 4 + lg) ^ (rb & 7)) << 3));
      }
#pragma unroll
      for (int m = 0; m < 4; ++m)
#pragma unroll
        for (int n = 0; n < 4; ++n)
          acc[m][n] = __builtin_amdgcn_mfma_f32_16x16x32_bf16(a[m], b[n], acc[m][n], 0, 0, 0);
    }
    __syncthreads();
  }

#pragma unroll
  for (int m = 0; m < 4; ++m) {
    int row0 = m0 + wr * 64 + m * 16 + lg * 4;
#pragma unroll
    for (int n = 0; n < 4; ++n) {
      int col = n0 + wc * 64 + n * 16 + lr;
      f32x4 c = acc[m][n];
      ushort4 pk;
      pk.x = f2bf(c[0]); pk.y = f2bf(c[1]); pk.z = f2bf(c[2]); pk.w = f2bf(c[3]);
      C[(size_t)(row0 + 0) * 1024 + col] = pk.x;
      C[(size_t)(row0 + 1) * 1024 + col] = pk.y;
      C[(size_t)(row0 + 2) * 1024 + col] = pk.z;
      C[(size_t)(row0 + 3) * 1024 + col] = pk.w;
      *reinterpret_cast<ushort4*>(Ct + (size_t)col * 1024 + row0) = pk;  // C^T
    }
  }
}

// ---------- Q8 = query . (Wa^8)^T : [4096x1024] x [1024x1024] NT, C only ----------
__global__ __launch_bounds__(256) void qgemm_kernel(const u16* __restrict__ A,
                                                    const u16* __restrict__ Bt,
                                                    u16* __restrict__ C) {
  __shared__ __align__(16) u16 As[8192];
  __shared__ __align__(16) u16 Bs[8192];

  int tid = threadIdx.x;
  int lane = tid & 63, wave = tid >> 6;
  int wr = wave >> 1, wc = wave & 1;
  int lr = lane & 15, lg = lane >> 4;
  int m0 = blockIdx.x * 128, n0 = blockIdx.y * 128;

  f32x4 acc[4][4];
  const f32x4 zero = {0.f, 0.f, 0.f, 0.f};
#pragma unroll
  for (int m = 0; m < 4; ++m)
#pragma unroll
    for (int n = 0; n < 4; ++n) acc[m][n] = zero;

  for (int k0 = 0; k0 < 1024; k0 += 64) {
    stage_tile(A + (size_t)m0 * 1024 + k0, 1024, As, tid);
    stage_tile(Bt + (size_t)n0 * 1024 + k0, 1024, Bs, tid);
    __syncthreads();
#pragma unroll
    for (int ks = 0; ks < 2; ++ks) {
      bf16x8 a[4], b[4];
#pragma unroll
      for (int m = 0; m < 4; ++m) {
        int ra = wr * 64 + m * 16 + lr;
        a[m] = *reinterpret_cast<const bf16x8*>(As + ra * 64 + (((ks * 4 + lg) ^ (ra & 7)) << 3));
      }
#pragma unroll
      for (int n = 0; n < 4; ++n) {
        int rb = wc * 64 + n * 16 + lr;
        b[n] = *reinterpret_cast<const bf16x8*>(Bs + rb * 64 + (((ks * 4 + lg) ^ (rb & 7)) << 3));
      }
#pragma unroll
      for (int m = 0; m < 4; ++m)
#pragma unroll
        for (int n = 0; n < 4; ++n)
          acc[m][n] = __builtin_amdgcn_mfma_f32_16x16x32_bf16(a[m], b[n], acc[m][n], 0, 0, 0);
    }
    __syncthreads();
  }

#pragma unroll
  for (int m = 0; m < 4; ++m) {
    int row0 = m0 + wr * 64 + m * 16 + lg * 4;
#pragma unroll
    for (int n = 0; n < 4; ++n) {
      int col = n0 + wc * 64 + n * 16 + lr;
      f32x4 c = acc[m][n];
      C[(size_t)(row0 + 0) * 1024 + col] = f2bf(c[0]);
      C[(size_t)(row0 + 1) * 1024 + col] = f2bf(c[1]);
      C[(size_t)(row0 + 2) * 1024 + col] = f2bf(c[2]);
      C[(size_t)(row0 + 3) * 1024 + col] = f2bf(c[3]);
    }
  }
}

// ---------- 64^2-tile variant for the small early power steps (fills the grid) ----------
__device__ __forceinline__ void stage_tile64(const u16* __restrict__ g, u16* lds, int tid) {
#pragma unroll
  for (int s = 0; s < 2; ++s) {
    int chunk = s * 256 + tid;                    // 512 chunks: 64 rows x 8
    int row = chunk >> 3;
    int kcl = (chunk & 7) ^ (row & 7);
    const u16* gp = g + (size_t)row * 1024 + (size_t)(kcl * 8);
    u16* lp = lds + (tid >> 6) * 512 + s * 2048;  // wave-uniform
    gload_lds16(gp, lp);
  }
}

__global__ __launch_bounds__(256) void pow64_gemm_kernel(PowArgs args) {
  const u16* A  = args.A[blockIdx.z];
  const u16* Bt = args.Bt[blockIdx.z];
  u16* C  = args.C[blockIdx.z];
  u16* Ct = args.Ct[blockIdx.z];

  __shared__ __align__(16) u16 As[4096];
  __shared__ __align__(16) u16 Bs[4096];

  int tid = threadIdx.x;
  int lane = tid & 63, wave = tid >> 6;
  int wr = wave >> 1, wc = wave & 1;
  int lr = lane & 15, lg = lane >> 4;
  int m0 = blockIdx.x * 64, n0 = blockIdx.y * 64;

  f32x4 acc[2][2];
  const f32x4 zero = {0.f, 0.f, 0.f, 0.f};
#pragma unroll
  for (int m = 0; m < 2; ++m)
#pragma unroll
    for (int n = 0; n < 2; ++n) acc[m][n] = zero;

  for (int k0 = 0; k0 < 1024; k0 += 64) {
    stage_tile64(A + (size_t)m0 * 1024 + k0, As, tid);
    stage_tile64(Bt + (size_t)n0 * 1024 + k0, Bs, tid);
    __syncthreads();
#pragma unroll
    for (int ks = 0; ks < 2; ++ks) {
      bf16x8 a[2], b[2];
#pragma unroll
      for (int m = 0; m < 2; ++m) {
        int ra = wr * 32 + m * 16 + lr;
        a[m] = *reinterpret_cast<const bf16x8*>(As + ra * 64 + (((ks * 4 + lg) ^ (ra & 7)) << 3));
      }
#pragma unroll
      for (int n = 0; n < 2; ++n) {
        int rb = wc * 32 + n * 16 + lr;
        b[n] = *reinterpret_cast<const bf16x8*>(Bs + rb * 64 + (((ks * 4 + lg) ^ (rb & 7)) << 3));
      }
#pragma unroll
      for (int m = 0; m < 2; ++m)
#pragma unroll
        for (int n = 0; n < 2; ++n)
          acc[m][n] = __builtin_amdgcn_mfma_f32_16x16x32_bf16(a[m], b[n], acc[m][n], 0, 0, 0);
    }
    __syncthreads();
  }

#pragma unroll
  for (int m = 0; m < 2; ++m) {
    int row0 = m0 + wr * 32 + m * 16 + lg * 4;
#pragma unroll
    for (int n = 0; n < 2; ++n) {
      int col = n0 + wc * 32 + n * 16 + lr;
      f32x4 c = acc[m][n];
      ushort4 pk;
      pk.x = f2bf(c[0]); pk.y = f2bf(c[1]); pk.z = f2bf(c[2]); pk.w = f2bf(c[3]);
      C[(size_t)(row0 + 0) * 1024 + col] = pk.x;
      C[(size_t)(row0 + 1) * 1024 + col] = pk.y;
      C[(size_t)(row0 + 2) * 1024 + col] = pk.z;
      C[(size_t)(row0 + 3) * 1024 + col] = pk.w;
      *reinterpret_cast<ushort4*>(Ct + (size_t)col * 1024 + row0) = pk;
    }
  }
}

// =====================================================================
// score8: fused score GEMM, 256x256 tile, BK=64, 8 waves.
// THIS ROUND: RELAXED schedule — no lgkmcnt(0)/sched_barrier/setprio
// pinning; one barrier per half-tile. Compiler interleaves ds_read
// with MFMA via its own counted lgkmcnt (m97/m141 evidence).
//
// LDS 128KB: A at [0,64K): [buf][ks][16KB]; B at [64K,128K): same.
// Region [256 rows][32 cols] bf16, XOR-swizzled (c ^= (row>>1)&3 on 16B
// chunks within 64B rows) on stage-source AND read (involution).
//
// Per tile kt (cur=kt&1, nxt=cur^1):
//  Q0: reads cur.ks0; stage (kt+1).ks1 -> nxt; MFMA ks0; BAR_A
//  Q1: reads cur.ks1; stage (kt+2).ks0 -> cur; MFMA ks1; [vmcnt(4)]; BAR_B
// Safety: every region's readers are MFMA-consumed (compiler lgkm) before
// the barrier that precedes its re-stage; reads cannot hoist above the
// tile-boundary vmcnt asm ("memory" fences both directions) => staged data
// guaranteed. vmcnt(4) at Q1 end retires 8 oldest of 12 => tile kt+1
// landed, 2 regions (kt+2 ks0) in flight. Prologue 12 loads, vmcnt(4).
// t >= 8 uses A = Q8 (= query.(Wa^8)^T) and F slot t-8 (Wa^{t+1} =
// Wa^{t-7}.Wa^8 commutes).
// =====================================================================

#define QPHASE(CUR, KS, STAGE_STMT, WAIT_STMT)                                        \
  { _Pragma("unroll") for (int m_ = 0; m_ < 8; ++m_)                                  \
      af[m_] = *reinterpret_cast<const bf16x8*>(lds + aoffv[m_] +                     \
                                                (CUR)*32768 + (KS)*16384);            \
    _Pragma("unroll") for (int n_ = 0; n_ < 4; ++n_)                                  \
      bfr[n_] = *reinterpret_cast<const bf16x8*>(lds + boffv[n_] +                    \
                                                 (CUR)*32768 + (KS)*16384);           \
    STAGE_STMT;                                                                       \
    _Pragma("unroll") for (int m_ = 0; m_ < 8; ++m_)                                  \
      _Pragma("unroll") for (int n_ = 0; n_ < 4; ++n_)                                \
        acc[m_][n_] =                                                                 \
            __builtin_amdgcn_mfma_f32_16x16x32_bf16(af[m_], bfr[n_], acc[m_][n_], 0, 0, 0); \
    WAIT_STMT;                                                                        \
    __builtin_amdgcn_s_barrier(); }

__global__ __launch_bounds__(512, 2) void score8_kernel(
    const u16* __restrict__ query_bf, const u16* __restrict__ q8_bf,
    const u16* __restrict__ topics_bf,
    const u16* __restrict__ F_base, const u16* __restrict__ Ua_bf,
    const float* __restrict__ va_w, float* __restrict__ scores_part) {
  extern __shared__ __align__(16) char lds[];

  const int tid = threadIdx.x;
  const int lane = tid & 63, wave = tid >> 6;
  const int wm = wave >> 2, wn = wave & 3;   // 2 x 4 wave grid
  const int lr = lane & 15, lg = lane >> 4;
  const int m0 = blockIdx.x * 256, n0 = blockIdx.y * 256;
  const int t = blockIdx.z;
  const int NT = 32;                          // K = 2048 = 32 tiles of 64

  const u16* Ft = F_base + (size_t)(t & 7) * (1024 * 1024);

  // --- precomputed per-thread ds_read byte offsets within a region ---
  u32 aoffv[8], boffv[4];
#pragma unroll
  for (int m = 0; m < 8; ++m) {
    int row = wm * 128 + m * 16 + lr;
    aoffv[m] = row * 64 + ((lg ^ ((row >> 1) & 3)) << 4);
  }
#pragma unroll
  for (int n = 0; n < 4; ++n) {
    int row = wn * 64 + n * 16 + lr;
    boffv[n] = 65536 + row * 64 + ((lg ^ ((row >> 1) & 3)) << 4);
  }

  // --- precomputed per-thread staging source offsets (elements) ---
  u32 goff1[2], goff2[2];
#pragma unroll
  for (int s = 0; s < 2; ++s) {
    int c = s * 512 + tid;
    int row = c >> 2;
    int cl = (c & 3) ^ ((row >> 1) & 3);      // inverse swizzle on source
    goff1[s] = row * 1024 + cl * 8;           // stride-1024 sources
    goff2[s] = row * 16384 + cl * 8;          // topics (stride 16384)
  }
  char* sdst = lds + (tid >> 6) * 1024;       // wave-uniform LDS dest base
  const u16* qbase = (t < 8 ? query_bf : q8_bf) + (size_t)m0 * 1024;
  const u16* tbase = topics_bf + (size_t)m0 * 16384 + (size_t)t * 1024 - 1024;
  const u16* fbase = Ft + (size_t)n0 * 1024;
  const u16* ubase = Ua_bf + (size_t)n0 * 1024 - 1024;

  auto stageA = [&](int kt, int ks, int buf) {
    const u16* base = (kt < 16 ? qbase : tbase) + kt * 64 + ks * 32;
#pragma unroll
    for (int s = 0; s < 2; ++s) {
      u32 off = (kt < 16) ? goff1[s] : goff2[s];
      gload_lds16(base + off, sdst + buf * 32768 + ks * 16384 + s * 8192);
    }
  };
  auto stageB = [&](int kt, int ks, int buf) {
    const u16* base = (kt < 16 ? fbase : ubase) + kt * 64 + ks * 32;
#pragma unroll
    for (int s = 0; s < 2; ++s)
      gload_lds16(base + goff1[s], sdst + 65536 + buf * 32768 + ks * 16384 + s * 8192);
  };

  f32x4 acc[8][4];
  const f32x4 zero = {0.f, 0.f, 0.f, 0.f};
#pragma unroll
  for (int m = 0; m < 8; ++m)
#pragma unroll
    for (int n = 0; n < 4; ++n) acc[m][n] = zero;

  bf16x8 af[8], bfr[4];

  // ---- prologue: tile0 full + tile1 ks0 (12 loads); vmcnt(4) => tile0 landed ----
  stageA(0, 0, 0); stageB(0, 0, 0);
  stageA(0, 1, 0); stageB(0, 1, 0);
  stageA(1, 0, 1); stageB(1, 0, 1);
  asm volatile("s_waitcnt vmcnt(4)" ::: "memory");
  __builtin_amdgcn_s_barrier();

  // ---- main loop: 2 half-tile phases per K-tile, relaxed scheduling ----
#pragma unroll 2
  for (int kt = 0; kt < NT; ++kt) {
    int cur = kt & 1, nxt = cur ^ 1;
    QPHASE(cur, 0,
           { if (kt + 1 < NT) { stageA(kt + 1, 1, nxt); stageB(kt + 1, 1, nxt); } },
           {});
    QPHASE(cur, 1,
           { if (kt + 2 < NT) { stageA(kt + 2, 0, cur); stageB(kt + 2, 0, cur); } },
           { if (kt < NT - 2)       { asm volatile("s_waitcnt vmcnt(4)" ::: "memory"); }
             else if (kt == NT - 2) { asm volatile("s_waitcnt vmcnt(0)" ::: "memory"); } });
  }

  // ---- epilogue: tanh, va-weight, row-reduce; per-y partial (no atomics) ----
  float va_c[4];
#pragma unroll
  for (int n = 0; n < 4; ++n) va_c[n] = va_w[n0 + wn * 64 + n * 16 + lr];

  float* sred = (float*)lds;  // staging fully drained; all waves past final barrier
#pragma unroll
  for (int m = 0; m < 8; ++m) {
    float rs[4] = {0.f, 0.f, 0.f, 0.f};
#pragma unroll
    for (int n = 0; n < 4; ++n) {
      f32x4 c = acc[m][n];
      rs[0] += va_c[n] * fast_tanh(c[0]);
      rs[1] += va_c[n] * fast_tanh(c[1]);
      rs[2] += va_c[n] * fast_tanh(c[2]);
      rs[3] += va_c[n] * fast_tanh(c[3]);
    }
#pragma unroll
    for (int j = 0; j < 4; ++j) {  // reduce over the 16 lr lanes
      float v = rs[j];
      v += __shfl_xor(v, 1);
      v += __shfl_xor(v, 2);
      v += __shfl_xor(v, 4);
      v += __shfl_xor(v, 8);
      if (lr == 0) sred[wn * 256 + wm * 128 + m * 16 + lg * 4 + j] = v;
    }
  }
  __syncthreads();
  if (tid < 256) {
    float s = sred[tid] + sred[256 + tid] + sred[512 + tid] + sred[768 + tid];
    scores_part[((size_t)blockIdx.y * 4096 + m0 + tid) * 16 + t] = s;
  }
}

// ---------- softmax over T + mt = alpha . topics ----------
__global__ __launch_bounds__(256) void softmax_mt_kernel(
    const float* __restrict__ scores_part, const float* __restrict__ cov,
    const float* __restrict__ topics, const float* __restrict__ va_b,
    float* __restrict__ mt, float* __restrict__ alphas) {
  int b = blockIdx.x;
  int tid = threadIdx.x;
  float vb = va_b[0];
  float e[16];
  float mx = -3.4e38f;
#pragma unroll
  for (int t = 0; t < 16; ++t) {
    float s = 0.f;
#pragma unroll
    for (int yy = 0; yy < 4; ++yy) s += scores_part[((size_t)yy * 4096 + b) * 16 + t];
    s = (s + vb) * cov[b * 16 + t];
    e[t] = s;
    mx = fmaxf(mx, s);
  }
  float sum = 0.f;
#pragma unroll
  for (int t = 0; t < 16; ++t) { e[t] = __expf(e[t] - mx); sum += e[t]; }
  float inv = 1.f / sum;
  if (tid == 0) {
#pragma unroll
    for (int t = 0; t < 16; ++t) alphas[b * 16 + t] = e[t] * inv;
  }
  const float4* tp = reinterpret_cast<const float4*>(topics + (size_t)b * 16384);
  float4 accv = {0.f, 0.f, 0.f, 0.f};
#pragma unroll
  for (int t = 0; t < 16; ++t) {
    float4 v = tp[t * 256 + tid];
    float a = e[t] * inv;
    accv.x += a * v.x; accv.y += a * v.y; accv.z += a * v.z; accv.w += a * v.w;
  }
  reinterpret_cast<float4*>(mt + (size_t)b * 1024)[tid] = accv;
}

// ---------- host orchestration ----------
extern "C" void kernel_launch(void* const* d_in, const int* in_sizes, int n_in,
                              void* d_out, int out_size, void* d_ws, size_t ws_size,
                              hipStream_t stream) {
  (void)in_sizes; (void)n_in; (void)out_size; (void)ws_size;
  const float* query = (const float*)d_in[0];
  const float* topics = (const float*)d_in[1];
  const float* cov   = (const float*)d_in[2];
  const float* Ua    = (const float*)d_in[3];
  const float* Wa    = (const float*)d_in[4];
  const float* va_w  = (const float*)d_in[5];
  const float* va_b  = (const float*)d_in[6];

  float* mt = (float*)d_out;
  float* alphas = mt + (size_t)4096 * 1024;

  char* ws = (char*)d_ws;
  u16* topics_bf = (u16*)(ws);                                  // 128 MB
  u16* query_bf  = (u16*)(ws + (size_t)128 * 1024 * 1024);      // 8 MB
  u16* Ua_bf     = (u16*)(ws + (size_t)136 * 1024 * 1024);      // 2 MB
  u16* F_base    = (u16*)(ws + (size_t)138 * 1024 * 1024);      // 16 MB : F[i] = Wa^(i+1), i<8
  u16* q8_bf     = (u16*)(ws + (size_t)154 * 1024 * 1024);      // 8 MB : query.(Wa^8)^T
  u16* FT_base   = (u16*)(ws + (size_t)170 * 1024 * 1024);      // 16 MB : transposes
  float* scores_part = (float*)(ws + (size_t)202 * 1024 * 1024); // 4 MB [y][b][t]

  hipFuncSetAttribute(reinterpret_cast<const void*>(score8_kernel),
                      hipFuncAttributeMaxDynamicSharedMemorySize, 131072);

  cvtall_kernel<<<15360, 256, 0, stream>>>(topics, topics_bf, query, query_bf,
                                           Ua, Ua_bf, Wa, F_base, FT_base);

  const size_t MS = 1024 * 1024;
  auto F  = [&](int i) { return F_base + (size_t)i * MS; };
  auto FT = [&](int i) { return FT_base + (size_t)i * MS; };

  // powers Wa^1..Wa^8: slot i holds Wa^(i+1)
  PowArgs a1{};
  a1.A[0] = F(0); a1.Bt[0] = FT(0); a1.C[0] = F(1); a1.Ct[0] = FT(1);            // Wa^2
  pow64_gemm_kernel<<<dim3(16, 16, 1), 256, 0, stream>>>(a1);
  PowArgs a2{};
  a2.A[0] = F(1); a2.Bt[0] = FT(0); a2.C[0] = F(2); a2.Ct[0] = FT(2);            // Wa^3
  a2.A[1] = F(1); a2.Bt[1] = FT(1); a2.C[1] = F(3); a2.Ct[1] = FT(3);            // Wa^4
  pow64_gemm_kernel<<<dim3(16, 16, 2), 256, 0, stream>>>(a2);
  PowArgs a3{};
  for (int p = 0; p < 4; ++p) { a3.A[p] = F(3); a3.Bt[p] = FT(p); a3.C[p] = F(4 + p); a3.Ct[p] = FT(4 + p); } // Wa^5..8
  pow_gemm_kernel<<<dim3(8, 8, 4), 256, 0, stream>>>(a3);

  // Q8 = query . (Wa^8)^T  (NT: Bt = Wa^8 row-major)
  qgemm_kernel<<<dim3(32, 8), 256, 0, stream>>>(query_bf, F(7), q8_bf);

  score8_kernel<<<dim3(16, 4, 16), 512, 131072, stream>>>(query_bf, q8_bf, topics_bf,
                                                          F_base, Ua_bf, va_w, scores_part);
  softmax_mt_kernel<<<4096, 256, 0, stream>>>(scores_part, cov, topics, va_b, mt, alphas);
}